// Round 2
// baseline (811.041 us; speedup 1.0000x reference)
//
#include <hip/hip_runtime.h>
#include <math.h>

#define SCALE_F 0.35355339059327373f   // 64^-0.25

typedef unsigned short u16;
typedef unsigned int   u32;
typedef _Float16 f16;
typedef _Float16 f16x8 __attribute__((ext_vector_type(8)));
typedef float    f32x4 __attribute__((ext_vector_type(4)));

__device__ __forceinline__ u16 f2h(float f) { f16 h = (f16)f; return *(u16*)&h; }
__device__ __forceinline__ float h2f(u16 b) { f16 h = *(f16*)&b; return (float)h; }

__device__ __forceinline__ void glds16(const u16* g, char* l) {
    __builtin_amdgcn_global_load_lds((const __attribute__((address_space(1))) void*)g,
                                     (__attribute__((address_space(3))) void*)l, 16, 0, 0);
}
__device__ __forceinline__ f32x4 mfma16(f16x8 a, f16x8 b, f32x4 c) {
    return __builtin_amdgcn_mfma_f32_16x16x32_f16(a, b, c, 0, 0, 0);
}

// ---------------------------------------------------------------------------
// to_f16: fp32 -> f16 elementwise (8 elems/thread).
// ---------------------------------------------------------------------------
__global__ __launch_bounds__(256) void to_f16(
    const float* __restrict__ X, u16* __restrict__ out)
{
    size_t i = ((size_t)blockIdx.x * 256 + threadIdx.x) * 8;
    float4 a = *(const float4*)(X + i);
    float4 b = *(const float4*)(X + i + 4);
    ushort4 r0, r1;
    r0.x = f2h(a.x); r0.y = f2h(a.y); r0.z = f2h(a.z); r0.w = f2h(a.w);
    r1.x = f2h(b.x); r1.y = f2h(b.y); r1.z = f2h(b.z); r1.w = f2h(b.w);
    *(ushort4*)(out + i)     = r0;
    *(ushort4*)(out + i + 4) = r1;
}

// ---------------------------------------------------------------------------
// transpose_f16: in [Z][R][C] fp32 -> out [Z][C][R] f16. 64x64 LDS tiles.
// ---------------------------------------------------------------------------
__global__ __launch_bounds__(256) void transpose_f16(
    const float* __restrict__ in, u16* __restrict__ out, int R, int C)
{
    __shared__ __align__(16) u16 T[64 * 80];
    const int c0 = blockIdx.x * 64, r0 = blockIdx.y * 64, z = blockIdx.z;
    const int t = threadIdx.x;
    const int rl = t >> 4, c4 = (t & 15) * 4;
    const float* base = in + (size_t)z * R * C;

    #pragma unroll
    for (int rr = 0; rr < 4; ++rr) {
        int r = rr * 16 + rl;
        float4 v = *(const float4*)(base + (size_t)(r0 + r) * C + c0 + c4);
        T[(c4 + 0) * 80 + r] = f2h(v.x);
        T[(c4 + 1) * 80 + r] = f2h(v.y);
        T[(c4 + 2) * 80 + r] = f2h(v.z);
        T[(c4 + 3) * 80 + r] = f2h(v.w);
    }
    __syncthreads();
    #pragma unroll
    for (int rep = 0; rep < 2; ++rep) {
        int idx = rep * 256 + t;
        int cl = idx >> 3, r8 = (idx & 7) * 8;
        *(float4*)(out + ((size_t)z * C + c0 + cl) * R + r0 + r8) =
            *(const float4*)&T[cl * 80 + r8];
    }
}

// ---------------------------------------------------------------------------
// qkv_mfma: Xh[65536,512](f16) @ WT(f16) + b.  128x128 tile, BK=32, 4 waves,
// 16x16x32 f16 MFMA, global_load_lds(16B) staging in chunk layout
// [k-octet][row].  nt 0-7 -> Q/K as f16 [bh][n][d]; nt 8-11 -> V transposed
// through LDS into Vt f16 [bh][d][n].
// ---------------------------------------------------------------------------
__global__ __launch_bounds__(256) void qkv_mfma(
    const u16* __restrict__ Xh, const u16* __restrict__ WT,
    const float* __restrict__ bias,
    u16* __restrict__ Q, u16* __restrict__ Kk, u16* __restrict__ Vt)
{
    __shared__ __align__(16) char smem[33280];   // As+Bs (16 KB); Tr[128][65] fp32 aliases
    char* As = smem;             // 512 chunks x 16B
    char* Bs = smem + 8192;

    const int nt = blockIdx.x, mt = blockIdx.y;
    const int t = threadIdx.x;
    const int wave = t >> 6, lane = t & 63;
    const int wm = wave & 1, wn = wave >> 1;
    const int quad = lane >> 4, l16 = lane & 15;
    const int m0 = mt * 128;

    const int c0 = wave * 128 + lane;            // staging chunk ids
    const int c1 = c0 + 64;
    const size_t xoff0 = (size_t)(m0 + (c0 & 127)) * 512 + (c0 >> 7) * 8;
    const size_t xoff1 = (size_t)(m0 + (c1 & 127)) * 512 + (c1 >> 7) * 8;
    const size_t woff0 = (size_t)(nt * 128 + (c0 & 127)) * 512 + (c0 >> 7) * 8;
    const size_t woff1 = (size_t)(nt * 128 + (c1 & 127)) * 512 + (c1 >> 7) * 8;
    const int lb0 = (wave * 128) * 16;           // wave-uniform LDS base
    const int lb1 = lb0 + 64 * 16;

    f32x4 acc[4][4];
    #pragma unroll
    for (int i = 0; i < 4; ++i)
        #pragma unroll
        for (int j = 0; j < 4; ++j) acc[i][j] = (f32x4){0.f, 0.f, 0.f, 0.f};

    for (int k0 = 0; k0 < 512; k0 += 32) {
        __syncthreads();
        glds16(Xh + xoff0 + k0, As + lb0);
        glds16(Xh + xoff1 + k0, As + lb1);
        glds16(WT + woff0 + k0, Bs + lb0);
        glds16(WT + woff1 + k0, Bs + lb1);
        __syncthreads();

        f16x8 af[4], bf[4];
        #pragma unroll
        for (int i = 0; i < 4; ++i)
            af[i] = *(const f16x8*)(As + (quad * 128 + wm * 64 + i * 16 + l16) * 16);
        #pragma unroll
        for (int j = 0; j < 4; ++j)
            bf[j] = *(const f16x8*)(Bs + (quad * 128 + wn * 64 + j * 16 + l16) * 16);
        #pragma unroll
        for (int i = 0; i < 4; ++i)
            #pragma unroll
            for (int j = 0; j < 4; ++j)
                acc[i][j] = mfma16(af[i], bf[j], acc[i][j]);
    }

    const int b   = m0 >> 12;
    const int nn0 = m0 & 4095;
    float bv[4];
    #pragma unroll
    for (int j = 0; j < 4; ++j) bv[j] = bias[nt * 128 + wn * 64 + j * 16 + l16];

    if (nt < 8) {
        u16* dst = (nt < 4) ? Q : Kk;
        const int colbase = (nt & 3) * 128;
        #pragma unroll
        for (int i = 0; i < 4; ++i) {
            const int rowb = wm * 64 + i * 16 + quad * 4;
            #pragma unroll
            for (int j = 0; j < 4; ++j) {
                const int col = colbase + wn * 64 + j * 16 + l16;
                const int h = col >> 6, d = col & 63;
                u16* p = dst + ((size_t)((b * 8 + h) * 4096 + nn0 + rowb)) * 64 + d;
                #pragma unroll
                for (int r = 0; r < 4; ++r)
                    p[(size_t)r * 64] = f2h(acc[i][j][r] + bv[j]);
            }
        }
    } else {
        float* Tr = (float*)smem;                // [128][65]
        #pragma unroll
        for (int g = 0; g < 2; ++g) {
            __syncthreads();
            if (wn == g) {
                #pragma unroll
                for (int i = 0; i < 4; ++i)
                    #pragma unroll
                    for (int j = 0; j < 4; ++j)
                        #pragma unroll
                        for (int r = 0; r < 4; ++r)
                            Tr[(wm * 64 + i * 16 + quad * 4 + r) * 65 + j * 16 + l16] =
                                acc[i][j][r] + bv[j];
            }
            __syncthreads();
            const int h = (nt & 3) * 2 + g;
            u16* dstv = Vt + ((size_t)(b * 8 + h) * 64) * 4096 + nn0;
            #pragma unroll
            for (int rep = 0; rep < 32; ++rep) {
                int idx = rep * 256 + t;
                int d = idx >> 7, rr = idx & 127;
                dstv[(size_t)d * 4096 + rr] = f2h(Tr[rr * 65 + d]);
            }
        }
    }
}

// ---------------------------------------------------------------------------
// attn_logits (MFMA, no-LDS main loop): f16 Q,K in, fp32 softmaxed logits out.
// mode 0 (row): a[i,j]  = softmax_j( SCALE * sum_{w,c} q[i,w,c] k[j,w,c] )
// mode 1 (col): bm[i,j] = softmax_j( SCALE * sum_{t,c} q[t,i,c] k[t,j,c] )
// 64x64 output, K=4096. 4 waves 2x2 (32x32/wave). MFMA fragments are loaded
// DIRECTLY global->register (16B aligned, per-lane addresses) — no LDS, no
// barriers, no races in the K loop. LDS (sm/red) only in softmax epilogue.
// ---------------------------------------------------------------------------
__global__ __launch_bounds__(256) void attn_logits(
    const u16* __restrict__ Q, const u16* __restrict__ Kk,
    float* __restrict__ Aout, float* __restrict__ Bmout)
{
    __shared__ float sm[64 * 68];
    __shared__ float red[128];

    const int bh   = blockIdx.x;
    const int mode = blockIdx.y;
    const int t    = threadIdx.x;
    const int wave = t >> 6, lane = t & 63;
    const int wr = wave & 1, wc = wave >> 1;     // 2x2 wave grid, 32x32 per wave
    const int quad = lane >> 4, l16 = lane & 15;

    const u16* Qb = Q  + (size_t)bh * 262144;
    const u16* Kb = Kk + (size_t)bh * 262144;

    const int rA0 = wr * 32 + l16, rA1 = rA0 + 16;   // A rows (Q)
    const int rB0 = wc * 32 + l16, rB1 = rB0 + 16;   // B rows (K)

    f32x4 acc[2][2];
    #pragma unroll
    for (int i = 0; i < 2; ++i)
        #pragma unroll
        for (int j = 0; j < 2; ++j) acc[i][j] = (f32x4){0.f, 0.f, 0.f, 0.f};

    if (mode == 0) {
        const u16* pA0 = Qb + (size_t)rA0 * 4096;
        const u16* pA1 = Qb + (size_t)rA1 * 4096;
        const u16* pB0 = Kb + (size_t)rB0 * 4096;
        const u16* pB1 = Kb + (size_t)rB1 * 4096;
        #pragma unroll 4
        for (int k0 = 0; k0 < 4096; k0 += 32) {
            const int kk = k0 + quad * 8;
            f16x8 a0 = *(const f16x8*)(pA0 + kk);
            f16x8 a1 = *(const f16x8*)(pA1 + kk);
            f16x8 b0 = *(const f16x8*)(pB0 + kk);
            f16x8 b1 = *(const f16x8*)(pB1 + kk);
            acc[0][0] = mfma16(a0, b0, acc[0][0]);
            acc[0][1] = mfma16(a0, b1, acc[0][1]);
            acc[1][0] = mfma16(a1, b0, acc[1][0]);
            acc[1][1] = mfma16(a1, b1, acc[1][1]);
        }
    } else {
        // k = t*64 + c ; addr = t*4096 + row*64 + c
        #pragma unroll 4
        for (int k0 = 0; k0 < 4096; k0 += 32) {
            const int kk = k0 + quad * 8;
            const size_t base = (size_t)(kk >> 6) * 4096 + (kk & 63);
            f16x8 a0 = *(const f16x8*)(Qb + base + rA0 * 64);
            f16x8 a1 = *(const f16x8*)(Qb + base + rA1 * 64);
            f16x8 b0 = *(const f16x8*)(Kb + base + rB0 * 64);
            f16x8 b1 = *(const f16x8*)(Kb + base + rB1 * 64);
            acc[0][0] = mfma16(a0, b0, acc[0][0]);
            acc[0][1] = mfma16(a0, b1, acc[0][1]);
            acc[1][0] = mfma16(a1, b0, acc[1][0]);
            acc[1][1] = mfma16(a1, b1, acc[1][1]);
        }
    }

    // epilogue: scale -> sm[64][68] -> row softmax -> out
    #pragma unroll
    for (int i = 0; i < 2; ++i)
        #pragma unroll
        for (int j = 0; j < 2; ++j)
            #pragma unroll
            for (int r = 0; r < 4; ++r)
                sm[(wr * 32 + i * 16 + quad * 4 + r) * 68 + wc * 32 + j * 16 + l16] =
                    acc[i][j][r] * SCALE_F;
    __syncthreads();
    if (t < 64) {
        float m = -1e30f;
        for (int j = 0; j < 64; ++j) m = fmaxf(m, sm[t * 68 + j]);
        float ssum = 0.f;
        for (int j = 0; j < 64; ++j) ssum += __expf(sm[t * 68 + j] - m);
        red[t] = m;
        red[64 + t] = 1.0f / ssum;
    }
    __syncthreads();
    float* Out = ((mode == 0) ? Aout : Bmout) + (size_t)bh * 4096;
    #pragma unroll
    for (int rep = 0; rep < 16; ++rep) {
        int idx = rep * 256 + t;
        int i = idx >> 6, j = idx & 63;
        Out[idx] = __expf(sm[i * 68 + j] - red[i]) * red[64 + i];
    }
}

// ---------------------------------------------------------------------------
// coupling: per (bh,c): out_c = A · (V_c · Bm^T).  V_c from f16 Vt [bh][d][n].
// Output Y fp32 in [b][cf][n] layout.
// ---------------------------------------------------------------------------
__global__ __launch_bounds__(256) void coupling(
    const u16* __restrict__ Vt, const float* __restrict__ Aatt,
    const float* __restrict__ Bm, float* __restrict__ Y)
{
    __shared__ float At[64 * 68];
    __shared__ float Bt[64 * 68];
    __shared__ float Vs[64 * 68];
    __shared__ float Ms[64 * 68];

    const int bh = blockIdx.x;
    const int cg = blockIdx.y;
    const int t  = threadIdx.x;
    const int tx = t & 15, ty = t >> 4;
    const int il = t >> 2;
    const int c0 = (t & 3) << 4;

    const float* Ab = Aatt + (size_t)bh * 4096;
    const float* Bb = Bm + (size_t)bh * 4096;
    const u16* Vb = Vt + (size_t)bh * 262144;
    float* Yb = Y + (size_t)bh * 262144;

    #pragma unroll
    for (int cc = 0; cc < 4; ++cc) {
        float4 v = *(const float4*)(Ab + (size_t)il * 64 + c0 + cc * 4);
        At[(c0 + cc * 4 + 0) * 68 + il] = v.x;
        At[(c0 + cc * 4 + 1) * 68 + il] = v.y;
        At[(c0 + cc * 4 + 2) * 68 + il] = v.z;
        At[(c0 + cc * 4 + 3) * 68 + il] = v.w;
        float4 w = *(const float4*)(Bb + (size_t)il * 64 + c0 + cc * 4);
        Bt[(c0 + cc * 4 + 0) * 68 + il] = w.x;
        Bt[(c0 + cc * 4 + 1) * 68 + il] = w.y;
        Bt[(c0 + cc * 4 + 2) * 68 + il] = w.z;
        Bt[(c0 + cc * 4 + 3) * 68 + il] = w.w;
    }

    for (int c = cg * 16; c < cg * 16 + 16; ++c) {
        __syncthreads();
        #pragma unroll
        for (int cc = 0; cc < 4; ++cc) {
            ushort4 v = *(const ushort4*)(Vb + (size_t)c * 4096 + il * 64 + c0 + cc * 4);
            Vs[(c0 + cc * 4 + 0) * 68 + il] = h2f(v.x);
            Vs[(c0 + cc * 4 + 1) * 68 + il] = h2f(v.y);
            Vs[(c0 + cc * 4 + 2) * 68 + il] = h2f(v.z);
            Vs[(c0 + cc * 4 + 3) * 68 + il] = h2f(v.w);
        }
        __syncthreads();
        float m1[4][4];
        #pragma unroll
        for (int i = 0; i < 4; ++i)
            #pragma unroll
            for (int j = 0; j < 4; ++j) m1[i][j] = 0.f;
        #pragma unroll
        for (int w = 0; w < 64; ++w) {
            float a[4], b[4];
            *(float4*)a = *(const float4*)&Vs[w * 68 + ty * 4];
            *(float4*)b = *(const float4*)&Bt[w * 68 + tx * 4];
            #pragma unroll
            for (int i = 0; i < 4; ++i)
                #pragma unroll
                for (int j = 0; j < 4; ++j)
                    m1[i][j] = fmaf(a[i], b[j], m1[i][j]);
        }
        #pragma unroll
        for (int i = 0; i < 4; ++i)
            *(float4*)&Ms[(ty * 4 + i) * 68 + tx * 4] =
                make_float4(m1[i][0], m1[i][1], m1[i][2], m1[i][3]);
        __syncthreads();
        float o2[4][4];
        #pragma unroll
        for (int i = 0; i < 4; ++i)
            #pragma unroll
            for (int j = 0; j < 4; ++j) o2[i][j] = 0.f;
        #pragma unroll
        for (int j = 0; j < 64; ++j) {
            float a[4], b[4];
            *(float4*)a = *(const float4*)&At[j * 68 + ty * 4];
            *(float4*)b = *(const float4*)&Ms[j * 68 + tx * 4];
            #pragma unroll
            for (int i = 0; i < 4; ++i)
                #pragma unroll
                for (int u = 0; u < 4; ++u)
                    o2[i][u] = fmaf(a[i], b[u], o2[i][u]);
        }
        #pragma unroll
        for (int i = 0; i < 4; ++i)
            *(float4*)&Yb[(size_t)c * 4096 + (ty * 4 + i) * 64 + tx * 4] =
                make_float4(o2[i][0], o2[i][1], o2[i][2], o2[i][3]);
    }
}

// ---------------------------------------------------------------------------
// proj_mfma: Ytb[65536,512](f16) @ WpT(f16) + b -> Out fp32 [65536,512].
// ---------------------------------------------------------------------------
__global__ __launch_bounds__(256) void proj_mfma(
    const u16* __restrict__ A, const u16* __restrict__ WT,
    const float* __restrict__ bias, float* __restrict__ Out)
{
    __shared__ __align__(16) char smem[16384];
    char* As = smem;
    char* Bs = smem + 8192;

    const int nt = blockIdx.x, mt = blockIdx.y;
    const int t = threadIdx.x;
    const int wave = t >> 6, lane = t & 63;
    const int wm = wave & 1, wn = wave >> 1;
    const int quad = lane >> 4, l16 = lane & 15;
    const int m0 = mt * 128;

    const int c0 = wave * 128 + lane;
    const int c1 = c0 + 64;
    const size_t aoff0 = (size_t)(m0 + (c0 & 127)) * 512 + (c0 >> 7) * 8;
    const size_t aoff1 = (size_t)(m0 + (c1 & 127)) * 512 + (c1 >> 7) * 8;
    const size_t woff0 = (size_t)(nt * 128 + (c0 & 127)) * 512 + (c0 >> 7) * 8;
    const size_t woff1 = (size_t)(nt * 128 + (c1 & 127)) * 512 + (c1 >> 7) * 8;
    const int lb0 = (wave * 128) * 16;
    const int lb1 = lb0 + 64 * 16;

    f32x4 acc[4][4];
    #pragma unroll
    for (int i = 0; i < 4; ++i)
        #pragma unroll
        for (int j = 0; j < 4; ++j) acc[i][j] = (f32x4){0.f, 0.f, 0.f, 0.f};

    for (int k0 = 0; k0 < 512; k0 += 32) {
        __syncthreads();
        glds16(A + aoff0 + k0,  As + lb0);
        glds16(A + aoff1 + k0,  As + lb1);
        glds16(WT + woff0 + k0, Bs + lb0);
        glds16(WT + woff1 + k0, Bs + lb1);
        __syncthreads();

        f16x8 af[4], bf[4];
        #pragma unroll
        for (int i = 0; i < 4; ++i)
            af[i] = *(const f16x8*)(As + (quad * 128 + wm * 64 + i * 16 + l16) * 16);
        #pragma unroll
        for (int j = 0; j < 4; ++j)
            bf[j] = *(const f16x8*)(Bs + (quad * 128 + wn * 64 + j * 16 + l16) * 16);
        #pragma unroll
        for (int i = 0; i < 4; ++i)
            #pragma unroll
            for (int j = 0; j < 4; ++j)
                acc[i][j] = mfma16(af[i], bf[j], acc[i][j]);
    }

    float bv[4];
    #pragma unroll
    for (int j = 0; j < 4; ++j) bv[j] = bias[nt * 128 + wn * 64 + j * 16 + l16];

    #pragma unroll
    for (int i = 0; i < 4; ++i) {
        const int rowb = m0 + wm * 64 + i * 16 + quad * 4;
        #pragma unroll
        for (int j = 0; j < 4; ++j) {
            const int col = nt * 128 + wn * 64 + j * 16 + l16;
            #pragma unroll
            for (int r = 0; r < 4; ++r)
                Out[(size_t)(rowb + r) * 512 + col] = acc[i][j][r] + bv[j];
        }
    }
}

// ---------------------------------------------------------------------------
extern "C" void kernel_launch(void* const* d_in, const int* in_sizes, int n_in,
                              void* d_out, int out_size, void* d_ws, size_t ws_size,
                              hipStream_t stream)
{
    const float* x     = (const float*)d_in[0];
    const float* Wqkv  = (const float*)d_in[1];
    const float* bqkv  = (const float*)d_in[2];
    const float* Wproj = (const float*)d_in[3];
    const float* bproj = (const float*)d_in[4];
    float* out = (float*)d_out;

    // Workspace (275 MB total; round-1's 407 MB was proven OK, round-2's 545 MB crashed):
    u16* Xh  = (u16*)d_ws;                  // 33554432 elems
    u16* Qh  = Xh + 33554432;
    u16* Kh  = Qh + 33554432;
    u16* Vth = Kh + 33554432;
    u16* WqT = Vth + 33554432;              // 786432
    u16* WpT = WqT + 786432;                // 262144
    float* Aa = (float*)(WpT + 262144);     // 524288 f
    float* Bm = Aa + 524288;                // 524288 f
    float* Yy = (float*)d_ws;               // 128 MB, aliases Xh+Qh (dead after attn)
    u16*   Ytb = Kh;                        // aliases Kh (dead after attn)

    to_f16        <<<16384, 256, 0, stream>>>(x, Xh);
    transpose_f16 <<<dim3(24, 8, 1),  256, 0, stream>>>(Wqkv,  WqT, 512, 1536);
    transpose_f16 <<<dim3(8, 8, 1),   256, 0, stream>>>(Wproj, WpT, 512, 512);
    qkv_mfma      <<<dim3(12, 512),   256, 0, stream>>>(Xh, WqT, bqkv, Qh, Kh, Vth);
    attn_logits   <<<dim3(128, 2),    256, 0, stream>>>(Qh, Kh, Aa, Bm);
    coupling      <<<dim3(128, 4),    256, 0, stream>>>(Vth, Aa, Bm, Yy);
    transpose_f16 <<<dim3(64, 8, 16), 256, 0, stream>>>(Yy, Ytb, 512, 4096);
    proj_mfma     <<<dim3(4, 512),    256, 0, stream>>>(Ytb, WpT, bproj, out);
}

// Round 3
// 714.736 us; speedup vs baseline: 1.1347x; 1.1347x over previous
//
#include <hip/hip_runtime.h>
#include <math.h>

#define SCALE_F 0.35355339059327373f   // 64^-0.25

typedef unsigned short u16;
typedef unsigned int   u32;
typedef _Float16 f16;
typedef _Float16 f16x8 __attribute__((ext_vector_type(8)));
typedef float    f32x4 __attribute__((ext_vector_type(4)));

__device__ __forceinline__ u16 f2h(float f) { f16 h = (f16)f; return *(u16*)&h; }
__device__ __forceinline__ float h2f(u16 b) { f16 h = *(f16*)&b; return (float)h; }

__device__ __forceinline__ void glds16(const u16* g, char* l) {
    __builtin_amdgcn_global_load_lds((const __attribute__((address_space(1))) void*)g,
                                     (__attribute__((address_space(3))) void*)l, 16, 0, 0);
}
__device__ __forceinline__ f32x4 mfma16(f16x8 a, f16x8 b, f32x4 c) {
    return __builtin_amdgcn_mfma_f32_16x16x32_f16(a, b, c, 0, 0, 0);
}

// ---------------------------------------------------------------------------
// to_f16: fp32 -> f16 elementwise (8 elems/thread).
// ---------------------------------------------------------------------------
__global__ __launch_bounds__(256) void to_f16(
    const float* __restrict__ X, u16* __restrict__ out)
{
    size_t i = ((size_t)blockIdx.x * 256 + threadIdx.x) * 8;
    float4 a = *(const float4*)(X + i);
    float4 b = *(const float4*)(X + i + 4);
    ushort4 r0, r1;
    r0.x = f2h(a.x); r0.y = f2h(a.y); r0.z = f2h(a.z); r0.w = f2h(a.w);
    r1.x = f2h(b.x); r1.y = f2h(b.y); r1.z = f2h(b.z); r1.w = f2h(b.w);
    *(ushort4*)(out + i)     = r0;
    *(ushort4*)(out + i + 4) = r1;
}

// ---------------------------------------------------------------------------
// transpose_f16: in [Z][R][C] fp32 -> out [Z][C][R] f16. 64x64 LDS tiles.
// ---------------------------------------------------------------------------
__global__ __launch_bounds__(256) void transpose_f16(
    const float* __restrict__ in, u16* __restrict__ out, int R, int C)
{
    __shared__ __align__(16) u16 T[64 * 80];
    const int c0 = blockIdx.x * 64, r0 = blockIdx.y * 64, z = blockIdx.z;
    const int t = threadIdx.x;
    const int rl = t >> 4, c4 = (t & 15) * 4;
    const float* base = in + (size_t)z * R * C;

    #pragma unroll
    for (int rr = 0; rr < 4; ++rr) {
        int r = rr * 16 + rl;
        float4 v = *(const float4*)(base + (size_t)(r0 + r) * C + c0 + c4);
        T[(c4 + 0) * 80 + r] = f2h(v.x);
        T[(c4 + 1) * 80 + r] = f2h(v.y);
        T[(c4 + 2) * 80 + r] = f2h(v.z);
        T[(c4 + 3) * 80 + r] = f2h(v.w);
    }
    __syncthreads();
    #pragma unroll
    for (int rep = 0; rep < 2; ++rep) {
        int idx = rep * 256 + t;
        int cl = idx >> 3, r8 = (idx & 7) * 8;
        *(float4*)(out + ((size_t)z * C + c0 + cl) * R + r0 + r8) =
            *(const float4*)&T[cl * 80 + r8];
    }
}

// ---------------------------------------------------------------------------
// transpose16: in [Z=16][512][4096] f16 -> out [Z][4096][512] f16.
// 64x64 tiles through padded LDS.
// ---------------------------------------------------------------------------
__global__ __launch_bounds__(256) void transpose16(
    const u16* __restrict__ in, u16* __restrict__ out)
{
    __shared__ __align__(16) u16 T[64 * 80];
    const int c0 = blockIdx.x * 64, r0 = blockIdx.y * 64, z = blockIdx.z;
    const int t = threadIdx.x;
    const int rl = t >> 3;          // 0..31
    const int c8 = (t & 7) * 8;     // col chunk base
    const u16* base = in + (size_t)z * 512 * 4096;

    #pragma unroll
    for (int rr = 0; rr < 2; ++rr) {
        int r = rr * 32 + rl;
        const u16* p = base + (size_t)(r0 + r) * 4096 + c0 + c8;
        ushort4 v0 = *(const ushort4*)(p);
        ushort4 v1 = *(const ushort4*)(p + 4);
        T[(c8 + 0) * 80 + r] = v0.x;
        T[(c8 + 1) * 80 + r] = v0.y;
        T[(c8 + 2) * 80 + r] = v0.z;
        T[(c8 + 3) * 80 + r] = v0.w;
        T[(c8 + 4) * 80 + r] = v1.x;
        T[(c8 + 5) * 80 + r] = v1.y;
        T[(c8 + 6) * 80 + r] = v1.z;
        T[(c8 + 7) * 80 + r] = v1.w;
    }
    __syncthreads();
    #pragma unroll
    for (int rep = 0; rep < 2; ++rep) {
        int idx = rep * 256 + t;
        int cl = idx >> 3, r8 = (idx & 7) * 8;
        *(float4*)(out + ((size_t)z * 4096 + c0 + cl) * 512 + r0 + r8) =
            *(const float4*)&T[cl * 80 + r8];
    }
}

// ---------------------------------------------------------------------------
// qkv_mfma: Xh[65536,512](f16) @ WT(f16) + b.  128x128 tile, BK=64, 4 waves,
// 16x16x32 f16 MFMA, global_load_lds(16B) staging in chunk layout
// [k-octet(8)][row(128)].  8 K-iterations (half the barrier drains of BK=32).
// nt 0-7 -> Q/K as f16 [bh][n][d]; nt 8-11 -> V transposed into Vt [bh][d][n].
// ---------------------------------------------------------------------------
__global__ __launch_bounds__(256) void qkv_mfma(
    const u16* __restrict__ Xh, const u16* __restrict__ WT,
    const float* __restrict__ bias,
    u16* __restrict__ Q, u16* __restrict__ Kk, u16* __restrict__ Vt)
{
    __shared__ __align__(16) char smem[33280];   // As+Bs (32 KB); Tr[128][65] fp32 aliases
    char* As = smem;             // 1024 chunks x 16B  ([oct 0..7][row 0..127])
    char* Bs = smem + 16384;

    const int nt = blockIdx.x, mt = blockIdx.y;
    const int t = threadIdx.x;
    const int wave = t >> 6, lane = t & 63;
    const int wm = wave & 1, wn = wave >> 1;
    const int quad = lane >> 4, l16 = lane & 15;
    const int m0 = mt * 128;

    // staging: set r (0..3): chunk = r*256 + wave*64 + lane
    //   -> row = wm*64 + lane (mod 128), oct = r*2 + wn
    size_t xoff[4], woff[4];
    int lb[4];
    #pragma unroll
    for (int r = 0; r < 4; ++r) {
        const int row = wm * 64 + lane;
        const int oct = r * 2 + wn;
        xoff[r] = (size_t)(m0 + row) * 512 + oct * 8;
        woff[r] = (size_t)(nt * 128 + row) * 512 + oct * 8;
        lb[r]   = (r * 256 + wave * 64) * 16;
    }

    f32x4 acc[4][4];
    #pragma unroll
    for (int i = 0; i < 4; ++i)
        #pragma unroll
        for (int j = 0; j < 4; ++j) acc[i][j] = (f32x4){0.f, 0.f, 0.f, 0.f};

    for (int k0 = 0; k0 < 512; k0 += 64) {
        __syncthreads();
        #pragma unroll
        for (int r = 0; r < 4; ++r) {
            glds16(Xh + xoff[r] + k0, As + lb[r]);
            glds16(WT + woff[r] + k0, Bs + lb[r]);
        }
        __syncthreads();

        #pragma unroll
        for (int ss = 0; ss < 2; ++ss) {
            f16x8 af[4], bf[4];
            #pragma unroll
            for (int i = 0; i < 4; ++i)
                af[i] = *(const f16x8*)(As + (((ss * 4 + quad) * 128) + wm * 64 + i * 16 + l16) * 16);
            #pragma unroll
            for (int j = 0; j < 4; ++j)
                bf[j] = *(const f16x8*)(Bs + (((ss * 4 + quad) * 128) + wn * 64 + j * 16 + l16) * 16);
            #pragma unroll
            for (int i = 0; i < 4; ++i)
                #pragma unroll
                for (int j = 0; j < 4; ++j)
                    acc[i][j] = mfma16(af[i], bf[j], acc[i][j]);
        }
    }

    const int b   = m0 >> 12;
    const int nn0 = m0 & 4095;
    float bv[4];
    #pragma unroll
    for (int j = 0; j < 4; ++j) bv[j] = bias[nt * 128 + wn * 64 + j * 16 + l16];

    if (nt < 8) {
        u16* dst = (nt < 4) ? Q : Kk;
        const int colbase = (nt & 3) * 128;
        #pragma unroll
        for (int i = 0; i < 4; ++i) {
            const int rowb = wm * 64 + i * 16 + quad * 4;
            #pragma unroll
            for (int j = 0; j < 4; ++j) {
                const int col = colbase + wn * 64 + j * 16 + l16;
                const int h = col >> 6, d = col & 63;
                u16* p = dst + ((size_t)((b * 8 + h) * 4096 + nn0 + rowb)) * 64 + d;
                #pragma unroll
                for (int r = 0; r < 4; ++r)
                    p[(size_t)r * 64] = f2h(acc[i][j][r] + bv[j]);
            }
        }
    } else {
        float* Tr = (float*)smem;                // [128][65]
        #pragma unroll
        for (int g = 0; g < 2; ++g) {
            __syncthreads();
            if (wn == g) {
                #pragma unroll
                for (int i = 0; i < 4; ++i)
                    #pragma unroll
                    for (int j = 0; j < 4; ++j)
                        #pragma unroll
                        for (int r = 0; r < 4; ++r)
                            Tr[(wm * 64 + i * 16 + quad * 4 + r) * 65 + j * 16 + l16] =
                                acc[i][j][r] + bv[j];
            }
            __syncthreads();
            const int h = (nt & 3) * 2 + g;
            u16* dstv = Vt + ((size_t)(b * 8 + h) * 64) * 4096 + nn0;
            #pragma unroll
            for (int rep = 0; rep < 32; ++rep) {
                int idx = rep * 256 + t;
                int d = idx >> 7, rr = idx & 127;
                dstv[(size_t)d * 4096 + rr] = f2h(Tr[rr * 65 + d]);
            }
        }
    }
}

// ---------------------------------------------------------------------------
// attn_logits (MFMA, no-LDS main loop): f16 Q,K in, fp32 softmaxed logits out.
// ---------------------------------------------------------------------------
__global__ __launch_bounds__(256) void attn_logits(
    const u16* __restrict__ Q, const u16* __restrict__ Kk,
    float* __restrict__ Aout, float* __restrict__ Bmout)
{
    __shared__ float sm[64 * 68];
    __shared__ float red[128];

    const int bh   = blockIdx.x;
    const int mode = blockIdx.y;
    const int t    = threadIdx.x;
    const int wave = t >> 6, lane = t & 63;
    const int wr = wave & 1, wc = wave >> 1;     // 2x2 wave grid, 32x32 per wave
    const int quad = lane >> 4, l16 = lane & 15;

    const u16* Qb = Q  + (size_t)bh * 262144;
    const u16* Kb = Kk + (size_t)bh * 262144;

    const int rA0 = wr * 32 + l16, rA1 = rA0 + 16;   // A rows (Q)
    const int rB0 = wc * 32 + l16, rB1 = rB0 + 16;   // B rows (K)

    f32x4 acc[2][2];
    #pragma unroll
    for (int i = 0; i < 2; ++i)
        #pragma unroll
        for (int j = 0; j < 2; ++j) acc[i][j] = (f32x4){0.f, 0.f, 0.f, 0.f};

    if (mode == 0) {
        const u16* pA0 = Qb + (size_t)rA0 * 4096;
        const u16* pA1 = Qb + (size_t)rA1 * 4096;
        const u16* pB0 = Kb + (size_t)rB0 * 4096;
        const u16* pB1 = Kb + (size_t)rB1 * 4096;
        #pragma unroll 4
        for (int k0 = 0; k0 < 4096; k0 += 32) {
            const int kk = k0 + quad * 8;
            f16x8 a0 = *(const f16x8*)(pA0 + kk);
            f16x8 a1 = *(const f16x8*)(pA1 + kk);
            f16x8 b0 = *(const f16x8*)(pB0 + kk);
            f16x8 b1 = *(const f16x8*)(pB1 + kk);
            acc[0][0] = mfma16(a0, b0, acc[0][0]);
            acc[0][1] = mfma16(a0, b1, acc[0][1]);
            acc[1][0] = mfma16(a1, b0, acc[1][0]);
            acc[1][1] = mfma16(a1, b1, acc[1][1]);
        }
    } else {
        #pragma unroll 4
        for (int k0 = 0; k0 < 4096; k0 += 32) {
            const int kk = k0 + quad * 8;
            const size_t base = (size_t)(kk >> 6) * 4096 + (kk & 63);
            f16x8 a0 = *(const f16x8*)(Qb + base + rA0 * 64);
            f16x8 a1 = *(const f16x8*)(Qb + base + rA1 * 64);
            f16x8 b0 = *(const f16x8*)(Kb + base + rB0 * 64);
            f16x8 b1 = *(const f16x8*)(Kb + base + rB1 * 64);
            acc[0][0] = mfma16(a0, b0, acc[0][0]);
            acc[0][1] = mfma16(a0, b1, acc[0][1]);
            acc[1][0] = mfma16(a1, b0, acc[1][0]);
            acc[1][1] = mfma16(a1, b1, acc[1][1]);
        }
    }

    #pragma unroll
    for (int i = 0; i < 2; ++i)
        #pragma unroll
        for (int j = 0; j < 2; ++j)
            #pragma unroll
            for (int r = 0; r < 4; ++r)
                sm[(wr * 32 + i * 16 + quad * 4 + r) * 68 + wc * 32 + j * 16 + l16] =
                    acc[i][j][r] * SCALE_F;
    __syncthreads();
    if (t < 64) {
        float m = -1e30f;
        for (int j = 0; j < 64; ++j) m = fmaxf(m, sm[t * 68 + j]);
        float ssum = 0.f;
        for (int j = 0; j < 64; ++j) ssum += __expf(sm[t * 68 + j] - m);
        red[t] = m;
        red[64 + t] = 1.0f / ssum;
    }
    __syncthreads();
    float* Out = ((mode == 0) ? Aout : Bmout) + (size_t)bh * 4096;
    #pragma unroll
    for (int rep = 0; rep < 16; ++rep) {
        int idx = rep * 256 + t;
        int i = idx >> 6, j = idx & 63;
        Out[idx] = __expf(sm[i * 68 + j] - red[i]) * red[64 + i];
    }
}

// ---------------------------------------------------------------------------
// coupling (MFMA): per (bh,c): out_c = A · (V_c · Bm^T).
//   GEMM1: tmpT[u][j] = sum_w Bm[u][w] * Vc[j][w]   (V rows direct from global)
//   GEMM2: out[i][u]  = sum_j A[i][j] * tmpT[u][j]
// A,Bm converted fp32->f16 into LDS once per block; tmpT double-buffered in
// LDS (one barrier per c).  Output f16 [bh][c][n], n = i*64 + u.
// 4 waves 2x2 (32x32 tile each), 16 c per block.
// ---------------------------------------------------------------------------
__global__ __launch_bounds__(256) void coupling(
    const u16* __restrict__ Vt, const float* __restrict__ Aatt,
    const float* __restrict__ Bm, u16* __restrict__ Yh)
{
    __shared__ __align__(16) u16 Ah[64 * 72];
    __shared__ __align__(16) u16 Bh[64 * 72];
    __shared__ __align__(16) u16 Tt[2][64 * 72];

    const int bh = blockIdx.x, cg = blockIdx.y;
    const int t = threadIdx.x;
    const int wave = t >> 6, lane = t & 63;
    const int wr = wave & 1, wc = wave >> 1;
    const int quad = lane >> 4, l16 = lane & 15;

    const float* Ab = Aatt + (size_t)bh * 4096;
    const float* Bb = Bm   + (size_t)bh * 4096;
    const u16*  Vb  = Vt   + (size_t)bh * 262144;
    u16* Yb = Yh + (size_t)bh * 262144;

    {   // A[i][j], Bm[u][w] -> f16 LDS row-major stride 72
        const int row = t >> 2;
        const int colb = (t & 3) * 16;
        #pragma unroll
        for (int q = 0; q < 4; ++q) {
            float4 va = *(const float4*)(Ab + (size_t)row * 64 + colb + q * 4);
            Ah[row * 72 + colb + q * 4 + 0] = f2h(va.x);
            Ah[row * 72 + colb + q * 4 + 1] = f2h(va.y);
            Ah[row * 72 + colb + q * 4 + 2] = f2h(va.z);
            Ah[row * 72 + colb + q * 4 + 3] = f2h(va.w);
            float4 vb = *(const float4*)(Bb + (size_t)row * 64 + colb + q * 4);
            Bh[row * 72 + colb + q * 4 + 0] = f2h(vb.x);
            Bh[row * 72 + colb + q * 4 + 1] = f2h(vb.y);
            Bh[row * 72 + colb + q * 4 + 2] = f2h(vb.z);
            Bh[row * 72 + colb + q * 4 + 3] = f2h(vb.w);
        }
    }
    __syncthreads();

    for (int ci = 0; ci < 16; ++ci) {
        const int c = cg * 16 + ci;
        u16* tb = &Tt[ci & 1][0];

        // GEMM1: rows u (from Bh), cols j (V rows from global), K = w (64)
        f32x4 acc1[2][2];
        #pragma unroll
        for (int i = 0; i < 2; ++i)
            #pragma unroll
            for (int j = 0; j < 2; ++j) acc1[i][j] = (f32x4){0.f, 0.f, 0.f, 0.f};
        #pragma unroll
        for (int s = 0; s < 2; ++s) {
            f16x8 a1[2], b1[2];
            #pragma unroll
            for (int i = 0; i < 2; ++i)
                a1[i] = *(const f16x8*)&Bh[(wr * 32 + i * 16 + l16) * 72 + s * 32 + quad * 8];
            #pragma unroll
            for (int j = 0; j < 2; ++j)
                b1[j] = *(const f16x8*)(Vb + (size_t)c * 4096 +
                                        (size_t)(wc * 32 + j * 16 + l16) * 64 + s * 32 + quad * 8);
            #pragma unroll
            for (int i = 0; i < 2; ++i)
                #pragma unroll
                for (int j = 0; j < 2; ++j)
                    acc1[i][j] = mfma16(a1[i], b1[j], acc1[i][j]);
        }
        // store tmpT[u][j] as f16
        #pragma unroll
        for (int i = 0; i < 2; ++i)
            #pragma unroll
            for (int j = 0; j < 2; ++j)
                #pragma unroll
                for (int r = 0; r < 4; ++r)
                    tb[(wr * 32 + i * 16 + quad * 4 + r) * 72 + wc * 32 + j * 16 + l16] =
                        f2h(acc1[i][j][r]);
        __syncthreads();

        // GEMM2: rows i (from Ah), cols u (tmpT rows), K = j (64)
        f32x4 acc2[2][2];
        #pragma unroll
        for (int i = 0; i < 2; ++i)
            #pragma unroll
            for (int j = 0; j < 2; ++j) acc2[i][j] = (f32x4){0.f, 0.f, 0.f, 0.f};
        #pragma unroll
        for (int s = 0; s < 2; ++s) {
            f16x8 a2[2], b2[2];
            #pragma unroll
            for (int i = 0; i < 2; ++i)
                a2[i] = *(const f16x8*)&Ah[(wr * 32 + i * 16 + l16) * 72 + s * 32 + quad * 8];
            #pragma unroll
            for (int u = 0; u < 2; ++u)
                b2[u] = *(const f16x8*)&tb[(wc * 32 + u * 16 + l16) * 72 + s * 32 + quad * 8];
            #pragma unroll
            for (int i = 0; i < 2; ++i)
                #pragma unroll
                for (int u = 0; u < 2; ++u)
                    acc2[i][u] = mfma16(a2[i], b2[u], acc2[i][u]);
        }
        // out[i][u] -> Yh[bh][c][i*64+u] f16
        #pragma unroll
        for (int i = 0; i < 2; ++i)
            #pragma unroll
            for (int u = 0; u < 2; ++u)
                #pragma unroll
                for (int r = 0; r < 4; ++r)
                    Yb[(size_t)c * 4096 + (wr * 32 + i * 16 + quad * 4 + r) * 64 +
                       wc * 32 + u * 16 + l16] = f2h(acc2[i][u][r]);
    }
}

// ---------------------------------------------------------------------------
// proj_mfma: Ytb[65536,512](f16) @ WpT(f16) + b -> Out fp32 [65536,512].
// BK=64 (8 K-iterations).
// ---------------------------------------------------------------------------
__global__ __launch_bounds__(256) void proj_mfma(
    const u16* __restrict__ A, const u16* __restrict__ WT,
    const float* __restrict__ bias, float* __restrict__ Out)
{
    __shared__ __align__(16) char smem[32768];
    char* As = smem;
    char* Bs = smem + 16384;

    const int nt = blockIdx.x, mt = blockIdx.y;
    const int t = threadIdx.x;
    const int wave = t >> 6, lane = t & 63;
    const int wm = wave & 1, wn = wave >> 1;
    const int quad = lane >> 4, l16 = lane & 15;
    const int m0 = mt * 128;

    size_t aoff[4], woff[4];
    int lb[4];
    #pragma unroll
    for (int r = 0; r < 4; ++r) {
        const int row = wm * 64 + lane;
        const int oct = r * 2 + wn;
        aoff[r] = (size_t)(m0 + row) * 512 + oct * 8;
        woff[r] = (size_t)(nt * 128 + row) * 512 + oct * 8;
        lb[r]   = (r * 256 + wave * 64) * 16;
    }

    f32x4 acc[4][4];
    #pragma unroll
    for (int i = 0; i < 4; ++i)
        #pragma unroll
        for (int j = 0; j < 4; ++j) acc[i][j] = (f32x4){0.f, 0.f, 0.f, 0.f};

    for (int k0 = 0; k0 < 512; k0 += 64) {
        __syncthreads();
        #pragma unroll
        for (int r = 0; r < 4; ++r) {
            glds16(A + aoff[r] + k0,  As + lb[r]);
            glds16(WT + woff[r] + k0, Bs + lb[r]);
        }
        __syncthreads();

        #pragma unroll
        for (int ss = 0; ss < 2; ++ss) {
            f16x8 af[4], bf[4];
            #pragma unroll
            for (int i = 0; i < 4; ++i)
                af[i] = *(const f16x8*)(As + (((ss * 4 + quad) * 128) + wm * 64 + i * 16 + l16) * 16);
            #pragma unroll
            for (int j = 0; j < 4; ++j)
                bf[j] = *(const f16x8*)(Bs + (((ss * 4 + quad) * 128) + wn * 64 + j * 16 + l16) * 16);
            #pragma unroll
            for (int i = 0; i < 4; ++i)
                #pragma unroll
                for (int j = 0; j < 4; ++j)
                    acc[i][j] = mfma16(af[i], bf[j], acc[i][j]);
        }
    }

    float bv[4];
    #pragma unroll
    for (int j = 0; j < 4; ++j) bv[j] = bias[nt * 128 + wn * 64 + j * 16 + l16];

    #pragma unroll
    for (int i = 0; i < 4; ++i) {
        const int rowb = m0 + wm * 64 + i * 16 + quad * 4;
        #pragma unroll
        for (int j = 0; j < 4; ++j) {
            const int col = nt * 128 + wn * 64 + j * 16 + l16;
            #pragma unroll
            for (int r = 0; r < 4; ++r)
                Out[(size_t)(rowb + r) * 512 + col] = acc[i][j][r] + bv[j];
        }
    }
}

// ---------------------------------------------------------------------------
extern "C" void kernel_launch(void* const* d_in, const int* in_sizes, int n_in,
                              void* d_out, int out_size, void* d_ws, size_t ws_size,
                              hipStream_t stream)
{
    const float* x     = (const float*)d_in[0];
    const float* Wqkv  = (const float*)d_in[1];
    const float* bqkv  = (const float*)d_in[2];
    const float* Wproj = (const float*)d_in[3];
    const float* bproj = (const float*)d_in[4];
    float* out = (float*)d_out;

    u16* Xh  = (u16*)d_ws;                  // 33554432 elems (64 MB)
    u16* Qh  = Xh + 33554432;
    u16* Kh  = Qh + 33554432;
    u16* Vth = Kh + 33554432;
    u16* WqT = Vth + 33554432;              // 786432
    u16* WpT = WqT + 786432;                // 262144
    float* Aa = (float*)(WpT + 262144);     // 524288 f
    float* Bm = Aa + 524288;                // 524288 f
    u16* Yh  = Xh;                          // 64 MB f16, aliases Xh (dead after qkv)
    u16* Ytb = Kh;                          // aliases Kh (dead after attn)

    to_f16        <<<16384, 256, 0, stream>>>(x, Xh);
    transpose_f16 <<<dim3(24, 8, 1),  256, 0, stream>>>(Wqkv,  WqT, 512, 1536);
    transpose_f16 <<<dim3(8, 8, 1),   256, 0, stream>>>(Wproj, WpT, 512, 512);
    qkv_mfma      <<<dim3(12, 512),   256, 0, stream>>>(Xh, WqT, bqkv, Qh, Kh, Vth);
    attn_logits   <<<dim3(128, 2),    256, 0, stream>>>(Qh, Kh, Aa, Bm);
    coupling      <<<dim3(128, 4),    256, 0, stream>>>(Vth, Aa, Bm, Yh);
    transpose16   <<<dim3(64, 8, 16), 256, 0, stream>>>(Yh, Ytb);
    proj_mfma     <<<dim3(4, 512),    256, 0, stream>>>(Ytb, WpT, bproj, out);
}

// Round 5
// 678.567 us; speedup vs baseline: 1.1952x; 1.0533x over previous
//
#include <hip/hip_runtime.h>
#include <math.h>

#define SCALE_F 0.35355339059327373f   // 64^-0.25

typedef unsigned short u16;
typedef unsigned int   u32;
typedef _Float16 f16;
typedef _Float16 f16x8 __attribute__((ext_vector_type(8)));
typedef float    f32x4 __attribute__((ext_vector_type(4)));

__device__ __forceinline__ u16 f2h(float f) { f16 h = (f16)f; return *(u16*)&h; }
__device__ __forceinline__ float h2f(u16 b) { f16 h = *(f16*)&b; return (float)h; }

__device__ __forceinline__ void glds16(const u16* g, char* l) {
    __builtin_amdgcn_global_load_lds((const __attribute__((address_space(1))) void*)g,
                                     (__attribute__((address_space(3))) void*)l, 16, 0, 0);
}
__device__ __forceinline__ f32x4 mfma16(f16x8 a, f16x8 b, f32x4 c) {
    return __builtin_amdgcn_mfma_f32_16x16x32_f16(a, b, c, 0, 0, 0);
}

// ---------------------------------------------------------------------------
// to_f16: fp32 -> f16 elementwise (8 elems/thread).
// ---------------------------------------------------------------------------
__global__ __launch_bounds__(256) void to_f16(
    const float* __restrict__ X, u16* __restrict__ out)
{
    size_t i = ((size_t)blockIdx.x * 256 + threadIdx.x) * 8;
    float4 a = *(const float4*)(X + i);
    float4 b = *(const float4*)(X + i + 4);
    ushort4 r0, r1;
    r0.x = f2h(a.x); r0.y = f2h(a.y); r0.z = f2h(a.z); r0.w = f2h(a.w);
    r1.x = f2h(b.x); r1.y = f2h(b.y); r1.z = f2h(b.z); r1.w = f2h(b.w);
    *(ushort4*)(out + i)     = r0;
    *(ushort4*)(out + i + 4) = r1;
}

// ---------------------------------------------------------------------------
// transpose_f16: in [Z][R][C] fp32 -> out [Z][C][R] f16. 64x64 LDS tiles.
// ---------------------------------------------------------------------------
__global__ __launch_bounds__(256) void transpose_f16(
    const float* __restrict__ in, u16* __restrict__ out, int R, int C)
{
    __shared__ __align__(16) u16 T[64 * 80];
    const int c0 = blockIdx.x * 64, r0 = blockIdx.y * 64, z = blockIdx.z;
    const int t = threadIdx.x;
    const int rl = t >> 4, c4 = (t & 15) * 4;
    const float* base = in + (size_t)z * R * C;

    #pragma unroll
    for (int rr = 0; rr < 4; ++rr) {
        int r = rr * 16 + rl;
        float4 v = *(const float4*)(base + (size_t)(r0 + r) * C + c0 + c4);
        T[(c4 + 0) * 80 + r] = f2h(v.x);
        T[(c4 + 1) * 80 + r] = f2h(v.y);
        T[(c4 + 2) * 80 + r] = f2h(v.z);
        T[(c4 + 3) * 80 + r] = f2h(v.w);
    }
    __syncthreads();
    #pragma unroll
    for (int rep = 0; rep < 2; ++rep) {
        int idx = rep * 256 + t;
        int cl = idx >> 3, r8 = (idx & 7) * 8;
        *(float4*)(out + ((size_t)z * C + c0 + cl) * R + r0 + r8) =
            *(const float4*)&T[cl * 80 + r8];
    }
}

// ---------------------------------------------------------------------------
// transpose16: in [Z=16][512][4096] f16 -> out [Z][4096][512] f16.
// 64x64 tiles through padded LDS.
// ---------------------------------------------------------------------------
__global__ __launch_bounds__(256) void transpose16(
    const u16* __restrict__ in, u16* __restrict__ out)
{
    __shared__ __align__(16) u16 T[64 * 80];
    const int c0 = blockIdx.x * 64, r0 = blockIdx.y * 64, z = blockIdx.z;
    const int t = threadIdx.x;
    const int rl = t >> 3;          // 0..31
    const int c8 = (t & 7) * 8;     // col chunk base
    const u16* base = in + (size_t)z * 512 * 4096;

    #pragma unroll
    for (int rr = 0; rr < 2; ++rr) {
        int r = rr * 32 + rl;
        const u16* p = base + (size_t)(r0 + r) * 4096 + c0 + c8;
        ushort4 v0 = *(const ushort4*)(p);
        ushort4 v1 = *(const ushort4*)(p + 4);
        T[(c8 + 0) * 80 + r] = v0.x;
        T[(c8 + 1) * 80 + r] = v0.y;
        T[(c8 + 2) * 80 + r] = v0.z;
        T[(c8 + 3) * 80 + r] = v0.w;
        T[(c8 + 4) * 80 + r] = v1.x;
        T[(c8 + 5) * 80 + r] = v1.y;
        T[(c8 + 6) * 80 + r] = v1.z;
        T[(c8 + 7) * 80 + r] = v1.w;
    }
    __syncthreads();
    #pragma unroll
    for (int rep = 0; rep < 2; ++rep) {
        int idx = rep * 256 + t;
        int cl = idx >> 3, r8 = (idx & 7) * 8;
        *(float4*)(out + ((size_t)z * 4096 + c0 + cl) * 512 + r0 + r8) =
            *(const float4*)&T[cl * 80 + r8];
    }
}

// ---------------------------------------------------------------------------
// qkv_mfma: Xh[65536,512](f16) @ WT(f16) + b.  128x128 tile, BK=32, 4 waves,
// 16x16x32 f16 MFMA.  DOUBLE-BUFFERED global_load_lds staging: next K-chunk
// issued BEFORE computing current -> load latency hidden under MFMA; one
// barrier per iteration (implicit vmcnt(0) drain lands after compute).
// 1-D grid with XCD-aware swizzle: the 12 same-mt blocks (sharing an X strip)
// land on one XCD's L2.
// nt 0-7 -> Q/K as f16 [bh][n][d]; nt 8-11 -> V transposed into Vt [bh][d][n].
// ---------------------------------------------------------------------------
__global__ __launch_bounds__(256) void qkv_mfma(
    const u16* __restrict__ Xh, const u16* __restrict__ WT,
    const float* __restrict__ bias,
    u16* __restrict__ Q, u16* __restrict__ Kk, u16* __restrict__ Vt)
{
    __shared__ __align__(16) char smem[33280];   // 2x(As 8K + Bs 8K); Tr[128][65] f32 aliases
    // buffer layout: buf c at smem + c*16384; As = +0 (8K), Bs = +8192 (8K)

    const int id  = blockIdx.x;                  // 0..6143
    const int xcd = id & 7;
    const int jj  = id >> 3;                     // 0..767
    const int mt  = xcd * 64 + jj / 12;          // same-mt group -> same XCD
    const int nt  = jj % 12;

    const int t = threadIdx.x;
    const int wave = t >> 6, lane = t & 63;
    const int wm = wave & 1, wn = wave >> 1;
    const int quad = lane >> 4, l16 = lane & 15;
    const int m0 = mt * 128;

    const int c0 = wave * 128 + lane;            // staging chunk ids (oct = c>>7, row = c&127)
    const int c1 = c0 + 64;
    const size_t xoff0 = (size_t)(m0 + (c0 & 127)) * 512 + (c0 >> 7) * 8;
    const size_t xoff1 = (size_t)(m0 + (c1 & 127)) * 512 + (c1 >> 7) * 8;
    const size_t woff0 = (size_t)(nt * 128 + (c0 & 127)) * 512 + (c0 >> 7) * 8;
    const size_t woff1 = (size_t)(nt * 128 + (c1 & 127)) * 512 + (c1 >> 7) * 8;
    const int lb0 = (wave * 128) * 16;           // wave-uniform LDS base (lane scatters x16B)
    const int lb1 = lb0 + 64 * 16;

    f32x4 acc[4][4];
    #pragma unroll
    for (int i = 0; i < 4; ++i)
        #pragma unroll
        for (int j = 0; j < 4; ++j) acc[i][j] = (f32x4){0.f, 0.f, 0.f, 0.f};

    // prologue: stage k0=0 into buffer 0
    glds16(Xh + xoff0, smem + lb0);
    glds16(Xh + xoff1, smem + lb1);
    glds16(WT + woff0, smem + 8192 + lb0);
    glds16(WT + woff1, smem + 8192 + lb1);
    __syncthreads();

    for (int k0 = 0; k0 < 512; k0 += 32) {
        const int co = (k0 & 32) << 9;           // alternates 0 / 16384
        const int cn = co ^ 16384;
        char* Ac = smem + co;
        char* Bc = smem + 8192 + co;
        if (k0 < 480) {                          // stage NEXT chunk before compute
            glds16(Xh + xoff0 + k0 + 32, smem + cn + lb0);
            glds16(Xh + xoff1 + k0 + 32, smem + cn + lb1);
            glds16(WT + woff0 + k0 + 32, smem + 8192 + cn + lb0);
            glds16(WT + woff1 + k0 + 32, smem + 8192 + cn + lb1);
        }

        f16x8 af[4], bf[4];
        #pragma unroll
        for (int i = 0; i < 4; ++i)
            af[i] = *(const f16x8*)(Ac + (quad * 128 + wm * 64 + i * 16 + l16) * 16);
        #pragma unroll
        for (int j = 0; j < 4; ++j)
            bf[j] = *(const f16x8*)(Bc + (quad * 128 + wn * 64 + j * 16 + l16) * 16);
        #pragma unroll
        for (int i = 0; i < 4; ++i)
            #pragma unroll
            for (int j = 0; j < 4; ++j)
                acc[i][j] = mfma16(af[i], bf[j], acc[i][j]);

        __syncthreads();   // drains next-chunk loads (after compute) + WAR protect
    }

    const int b   = m0 >> 12;
    const int nn0 = m0 & 4095;
    float bv[4];
    #pragma unroll
    for (int j = 0; j < 4; ++j) bv[j] = bias[nt * 128 + wn * 64 + j * 16 + l16];

    if (nt < 8) {
        u16* dst = (nt < 4) ? Q : Kk;
        const int colbase = (nt & 3) * 128;
        #pragma unroll
        for (int i = 0; i < 4; ++i) {
            const int rowb = wm * 64 + i * 16 + quad * 4;
            #pragma unroll
            for (int j = 0; j < 4; ++j) {
                const int col = colbase + wn * 64 + j * 16 + l16;
                const int h = col >> 6, d = col & 63;
                u16* p = dst + ((size_t)((b * 8 + h) * 4096 + nn0 + rowb)) * 64 + d;
                #pragma unroll
                for (int r = 0; r < 4; ++r)
                    p[(size_t)r * 64] = f2h(acc[i][j][r] + bv[j]);
            }
        }
    } else {
        float* Tr = (float*)smem;                // [128][65]
        #pragma unroll
        for (int g = 0; g < 2; ++g) {
            __syncthreads();
            if (wn == g) {
                #pragma unroll
                for (int i = 0; i < 4; ++i)
                    #pragma unroll
                    for (int j = 0; j < 4; ++j)
                        #pragma unroll
                        for (int r = 0; r < 4; ++r)
                            Tr[(wm * 64 + i * 16 + quad * 4 + r) * 65 + j * 16 + l16] =
                                acc[i][j][r] + bv[j];
            }
            __syncthreads();
            const int h = (nt & 3) * 2 + g;
            u16* dstv = Vt + ((size_t)(b * 8 + h) * 64) * 4096 + nn0;
            #pragma unroll
            for (int rep = 0; rep < 32; ++rep) {
                int idx = rep * 256 + t;
                int d = idx >> 7, rr = idx & 127;
                dstv[(size_t)d * 4096 + rr] = f2h(Tr[rr * 65 + d]);
            }
        }
    }
}

// ---------------------------------------------------------------------------
// attn_logits (MFMA, no-LDS main loop): f16 Q,K in, fp32 softmaxed logits out.
// ---------------------------------------------------------------------------
__global__ __launch_bounds__(256) void attn_logits(
    const u16* __restrict__ Q, const u16* __restrict__ Kk,
    float* __restrict__ Aout, float* __restrict__ Bmout)
{
    __shared__ float sm[64 * 68];
    __shared__ float red[128];

    const int bh   = blockIdx.x;
    const int mode = blockIdx.y;
    const int t    = threadIdx.x;
    const int wave = t >> 6, lane = t & 63;
    const int wr = wave & 1, wc = wave >> 1;     // 2x2 wave grid, 32x32 per wave
    const int quad = lane >> 4, l16 = lane & 15;

    const u16* Qb = Q  + (size_t)bh * 262144;
    const u16* Kb = Kk + (size_t)bh * 262144;

    const int rA0 = wr * 32 + l16, rA1 = rA0 + 16;   // A rows (Q)
    const int rB0 = wc * 32 + l16, rB1 = rB0 + 16;   // B rows (K)

    f32x4 acc[2][2];
    #pragma unroll
    for (int i = 0; i < 2; ++i)
        #pragma unroll
        for (int j = 0; j < 2; ++j) acc[i][j] = (f32x4){0.f, 0.f, 0.f, 0.f};

    if (mode == 0) {
        const u16* pA0 = Qb + (size_t)rA0 * 4096;
        const u16* pA1 = Qb + (size_t)rA1 * 4096;
        const u16* pB0 = Kb + (size_t)rB0 * 4096;
        const u16* pB1 = Kb + (size_t)rB1 * 4096;
        #pragma unroll 4
        for (int k0 = 0; k0 < 4096; k0 += 32) {
            const int kk = k0 + quad * 8;
            f16x8 a0 = *(const f16x8*)(pA0 + kk);
            f16x8 a1 = *(const f16x8*)(pA1 + kk);
            f16x8 b0 = *(const f16x8*)(pB0 + kk);
            f16x8 b1 = *(const f16x8*)(pB1 + kk);
            acc[0][0] = mfma16(a0, b0, acc[0][0]);
            acc[0][1] = mfma16(a0, b1, acc[0][1]);
            acc[1][0] = mfma16(a1, b0, acc[1][0]);
            acc[1][1] = mfma16(a1, b1, acc[1][1]);
        }
    } else {
        #pragma unroll 4
        for (int k0 = 0; k0 < 4096; k0 += 32) {
            const int kk = k0 + quad * 8;
            const size_t base = (size_t)(kk >> 6) * 4096 + (kk & 63);
            f16x8 a0 = *(const f16x8*)(Qb + base + rA0 * 64);
            f16x8 a1 = *(const f16x8*)(Qb + base + rA1 * 64);
            f16x8 b0 = *(const f16x8*)(Kb + base + rB0 * 64);
            f16x8 b1 = *(const f16x8*)(Kb + base + rB1 * 64);
            acc[0][0] = mfma16(a0, b0, acc[0][0]);
            acc[0][1] = mfma16(a0, b1, acc[0][1]);
            acc[1][0] = mfma16(a1, b0, acc[1][0]);
            acc[1][1] = mfma16(a1, b1, acc[1][1]);
        }
    }

    #pragma unroll
    for (int i = 0; i < 2; ++i)
        #pragma unroll
        for (int j = 0; j < 2; ++j)
            #pragma unroll
            for (int r = 0; r < 4; ++r)
                sm[(wr * 32 + i * 16 + quad * 4 + r) * 68 + wc * 32 + j * 16 + l16] =
                    acc[i][j][r] * SCALE_F;
    __syncthreads();
    if (t < 64) {
        float m = -1e30f;
        for (int j = 0; j < 64; ++j) m = fmaxf(m, sm[t * 68 + j]);
        float ssum = 0.f;
        for (int j = 0; j < 64; ++j) ssum += __expf(sm[t * 68 + j] - m);
        red[t] = m;
        red[64 + t] = 1.0f / ssum;
    }
    __syncthreads();
    float* Out = ((mode == 0) ? Aout : Bmout) + (size_t)bh * 4096;
    #pragma unroll
    for (int rep = 0; rep < 16; ++rep) {
        int idx = rep * 256 + t;
        int i = idx >> 6, j = idx & 63;
        Out[idx] = __expf(sm[i * 68 + j] - red[i]) * red[64 + i];
    }
}

// ---------------------------------------------------------------------------
// coupling (MFMA): per (bh,c): out_c = A · (V_c · Bm^T).
//   GEMM1: tmpT[u][j] = sum_w Bm[u][w] * Vc[j][w]   (V rows direct from global)
//   GEMM2: out[i][u]  = sum_j A[i][j] * tmpT[u][j]
// A,Bm converted fp32->f16 into LDS once per block; tmpT double-buffered in
// LDS (one barrier per c).  Output f16 [bh][c][n], n = i*64 + u.
// 4 waves 2x2 (32x32 tile each), 16 c per block.
// ---------------------------------------------------------------------------
__global__ __launch_bounds__(256) void coupling(
    const u16* __restrict__ Vt, const float* __restrict__ Aatt,
    const float* __restrict__ Bm, u16* __restrict__ Yh)
{
    __shared__ __align__(16) u16 Ah[64 * 72];
    __shared__ __align__(16) u16 Bh[64 * 72];
    __shared__ __align__(16) u16 Tt[2][64 * 72];

    const int bh = blockIdx.x, cg = blockIdx.y;
    const int t = threadIdx.x;
    const int wave = t >> 6, lane = t & 63;
    const int wr = wave & 1, wc = wave >> 1;
    const int quad = lane >> 4, l16 = lane & 15;

    const float* Ab = Aatt + (size_t)bh * 4096;
    const float* Bb = Bm   + (size_t)bh * 4096;
    const u16*  Vb  = Vt   + (size_t)bh * 262144;
    u16* Yb = Yh + (size_t)bh * 262144;

    {   // A[i][j], Bm[u][w] -> f16 LDS row-major stride 72
        const int row = t >> 2;
        const int colb = (t & 3) * 16;
        #pragma unroll
        for (int q = 0; q < 4; ++q) {
            float4 va = *(const float4*)(Ab + (size_t)row * 64 + colb + q * 4);
            Ah[row * 72 + colb + q * 4 + 0] = f2h(va.x);
            Ah[row * 72 + colb + q * 4 + 1] = f2h(va.y);
            Ah[row * 72 + colb + q * 4 + 2] = f2h(va.z);
            Ah[row * 72 + colb + q * 4 + 3] = f2h(va.w);
            float4 vb = *(const float4*)(Bb + (size_t)row * 64 + colb + q * 4);
            Bh[row * 72 + colb + q * 4 + 0] = f2h(vb.x);
            Bh[row * 72 + colb + q * 4 + 1] = f2h(vb.y);
            Bh[row * 72 + colb + q * 4 + 2] = f2h(vb.z);
            Bh[row * 72 + colb + q * 4 + 3] = f2h(vb.w);
        }
    }
    __syncthreads();

    for (int ci = 0; ci < 16; ++ci) {
        const int c = cg * 16 + ci;
        u16* tb = &Tt[ci & 1][0];

        // GEMM1: rows u (from Bh), cols j (V rows from global), K = w (64)
        f32x4 acc1[2][2];
        #pragma unroll
        for (int i = 0; i < 2; ++i)
            #pragma unroll
            for (int j = 0; j < 2; ++j) acc1[i][j] = (f32x4){0.f, 0.f, 0.f, 0.f};
        #pragma unroll
        for (int s = 0; s < 2; ++s) {
            f16x8 a1[2], b1[2];
            #pragma unroll
            for (int i = 0; i < 2; ++i)
                a1[i] = *(const f16x8*)&Bh[(wr * 32 + i * 16 + l16) * 72 + s * 32 + quad * 8];
            #pragma unroll
            for (int j = 0; j < 2; ++j)
                b1[j] = *(const f16x8*)(Vb + (size_t)c * 4096 +
                                        (size_t)(wc * 32 + j * 16 + l16) * 64 + s * 32 + quad * 8);
            #pragma unroll
            for (int i = 0; i < 2; ++i)
                #pragma unroll
                for (int j = 0; j < 2; ++j)
                    acc1[i][j] = mfma16(a1[i], b1[j], acc1[i][j]);
        }
        // store tmpT[u][j] as f16
        #pragma unroll
        for (int i = 0; i < 2; ++i)
            #pragma unroll
            for (int j = 0; j < 2; ++j)
                #pragma unroll
                for (int r = 0; r < 4; ++r)
                    tb[(wr * 32 + i * 16 + quad * 4 + r) * 72 + wc * 32 + j * 16 + l16] =
                        f2h(acc1[i][j][r]);
        __syncthreads();

        // GEMM2: rows i (from Ah), cols u (tmpT rows), K = j (64)
        f32x4 acc2[2][2];
        #pragma unroll
        for (int i = 0; i < 2; ++i)
            #pragma unroll
            for (int j = 0; j < 2; ++j) acc2[i][j] = (f32x4){0.f, 0.f, 0.f, 0.f};
        #pragma unroll
        for (int s = 0; s < 2; ++s) {
            f16x8 a2[2], b2[2];
            #pragma unroll
            for (int i = 0; i < 2; ++i)
                a2[i] = *(const f16x8*)&Ah[(wr * 32 + i * 16 + l16) * 72 + s * 32 + quad * 8];
            #pragma unroll
            for (int u = 0; u < 2; ++u)
                b2[u] = *(const f16x8*)&tb[(wc * 32 + u * 16 + l16) * 72 + s * 32 + quad * 8];
            #pragma unroll
            for (int i = 0; i < 2; ++i)
                #pragma unroll
                for (int u = 0; u < 2; ++u)
                    acc2[i][u] = mfma16(a2[i], b2[u], acc2[i][u]);
        }
        // out[i][u] -> Yh[bh][c][i*64+u] f16
        #pragma unroll
        for (int i = 0; i < 2; ++i)
            #pragma unroll
            for (int u = 0; u < 2; ++u)
                #pragma unroll
                for (int r = 0; r < 4; ++r)
                    Yb[(size_t)c * 4096 + (wr * 32 + i * 16 + quad * 4 + r) * 64 +
                       wc * 32 + u * 16 + l16] = f2h(acc2[i][u][r]);
    }
}

// ---------------------------------------------------------------------------
// proj_mfma: Ytb[65536,512](f16) @ WpT(f16) + b -> Out fp32 [65536,512].
// BK=32, double-buffered stage-ahead (same schedule as qkv_mfma), XCD swizzle.
// ---------------------------------------------------------------------------
__global__ __launch_bounds__(256) void proj_mfma(
    const u16* __restrict__ A, const u16* __restrict__ WT,
    const float* __restrict__ bias, float* __restrict__ Out)
{
    __shared__ __align__(16) char smem[32768];   // 2x(As 8K + Bs 8K)

    const int id  = blockIdx.x;                  // 0..2047
    const int xcd = id & 7;
    const int jj  = id >> 3;                     // 0..255
    const int mt  = xcd * 64 + (jj >> 2);
    const int nt  = jj & 3;

    const int t = threadIdx.x;
    const int wave = t >> 6, lane = t & 63;
    const int wm = wave & 1, wn = wave >> 1;
    const int quad = lane >> 4, l16 = lane & 15;
    const int m0 = mt * 128;

    const int c0 = wave * 128 + lane;
    const int c1 = c0 + 64;
    const size_t aoff0 = (size_t)(m0 + (c0 & 127)) * 512 + (c0 >> 7) * 8;
    const size_t aoff1 = (size_t)(m0 + (c1 & 127)) * 512 + (c1 >> 7) * 8;
    const size_t woff0 = (size_t)(nt * 128 + (c0 & 127)) * 512 + (c0 >> 7) * 8;
    const size_t woff1 = (size_t)(nt * 128 + (c1 & 127)) * 512 + (c1 >> 7) * 8;
    const int lb0 = (wave * 128) * 16;
    const int lb1 = lb0 + 64 * 16;

    f32x4 acc[4][4];
    #pragma unroll
    for (int i = 0; i < 4; ++i)
        #pragma unroll
        for (int j = 0; j < 4; ++j) acc[i][j] = (f32x4){0.f, 0.f, 0.f, 0.f};

    glds16(A  + aoff0, smem + lb0);
    glds16(A  + aoff1, smem + lb1);
    glds16(WT + woff0, smem + 8192 + lb0);
    glds16(WT + woff1, smem + 8192 + lb1);
    __syncthreads();

    for (int k0 = 0; k0 < 512; k0 += 32) {
        const int co = (k0 & 32) << 9;
        const int cn = co ^ 16384;
        char* Ac = smem + co;
        char* Bc = smem + 8192 + co;
        if (k0 < 480) {
            glds16(A  + aoff0 + k0 + 32, smem + cn + lb0);
            glds16(A  + aoff1 + k0 + 32, smem + cn + lb1);
            glds16(WT + woff0 + k0 + 32, smem + 8192 + cn + lb0);
            glds16(WT + woff1 + k0 + 32, smem + 8192 + cn + lb1);
        }

        f16x8 af[4], bf[4];
        #pragma unroll
        for (int i = 0; i < 4; ++i)
            af[i] = *(const f16x8*)(Ac + (quad * 128 + wm * 64 + i * 16 + l16) * 16);
        #pragma unroll
        for (int j = 0; j < 4; ++j)
            bf[j] = *(const f16x8*)(Bc + (quad * 128 + wn * 64 + j * 16 + l16) * 16);
        #pragma unroll
        for (int i = 0; i < 4; ++i)
            #pragma unroll
            for (int j = 0; j < 4; ++j)
                acc[i][j] = mfma16(af[i], bf[j], acc[i][j]);

        __syncthreads();
    }

    float bv[4];
    #pragma unroll
    for (int j = 0; j < 4; ++j) bv[j] = bias[nt * 128 + wn * 64 + j * 16 + l16];

    #pragma unroll
    for (int i = 0; i < 4; ++i) {
        const int rowb = m0 + wm * 64 + i * 16 + quad * 4;
        #pragma unroll
        for (int j = 0; j < 4; ++j) {
            const int col = nt * 128 + wn * 64 + j * 16 + l16;
            #pragma unroll
            for (int r = 0; r < 4; ++r)
                Out[(size_t)(rowb + r) * 512 + col] = acc[i][j][r] + bv[j];
        }
    }
}

// ---------------------------------------------------------------------------
extern "C" void kernel_launch(void* const* d_in, const int* in_sizes, int n_in,
                              void* d_out, int out_size, void* d_ws, size_t ws_size,
                              hipStream_t stream)
{
    const float* x     = (const float*)d_in[0];
    const float* Wqkv  = (const float*)d_in[1];
    const float* bqkv  = (const float*)d_in[2];
    const float* Wproj = (const float*)d_in[3];
    const float* bproj = (const float*)d_in[4];
    float* out = (float*)d_out;

    u16* Xh  = (u16*)d_ws;                  // 33554432 elems (64 MB)
    u16* Qh  = Xh + 33554432;
    u16* Kh  = Qh + 33554432;
    u16* Vth = Kh + 33554432;
    u16* WqT = Vth + 33554432;              // 786432
    u16* WpT = WqT + 786432;                // 262144
    float* Aa = (float*)(WpT + 262144);     // 524288 f
    float* Bm = Aa + 524288;                // 524288 f
    u16* Yh  = Xh;                          // 64 MB f16, aliases Xh (dead after qkv)
    u16* Ytb = Kh;                          // aliases Kh (dead after attn)

    to_f16        <<<16384, 256, 0, stream>>>(x, Xh);
    transpose_f16 <<<dim3(24, 8, 1),  256, 0, stream>>>(Wqkv,  WqT, 512, 1536);
    transpose_f16 <<<dim3(8, 8, 1),   256, 0, stream>>>(Wproj, WpT, 512, 512);
    qkv_mfma      <<<6144,            256, 0, stream>>>(Xh, WqT, bqkv, Qh, Kh, Vth);
    attn_logits   <<<dim3(128, 2),    256, 0, stream>>>(Qh, Kh, Aa, Bm);
    coupling      <<<dim3(128, 4),    256, 0, stream>>>(Vth, Aa, Bm, Yh);
    transpose16   <<<dim3(64, 8, 16), 256, 0, stream>>>(Yh, Ytb);
    proj_mfma     <<<2048,            256, 0, stream>>>(Ytb, WpT, bproj, out);
}

// Round 6
// 663.528 us; speedup vs baseline: 1.2223x; 1.0227x over previous
//
#include <hip/hip_runtime.h>
#include <math.h>

#define SCALE_F 0.35355339059327373f   // 64^-0.25

typedef unsigned short u16;
typedef unsigned int   u32;
typedef _Float16 f16;
typedef _Float16 f16x8 __attribute__((ext_vector_type(8)));
typedef float    f32x4 __attribute__((ext_vector_type(4)));

__device__ __forceinline__ u16 f2h(float f) { f16 h = (f16)f; return *(u16*)&h; }
__device__ __forceinline__ float h2f(u16 b) { f16 h = *(f16*)&b; return (float)h; }

__device__ __forceinline__ void glds16(const u16* g, char* l) {
    __builtin_amdgcn_global_load_lds((const __attribute__((address_space(1))) void*)g,
                                     (__attribute__((address_space(3))) void*)l, 16, 0, 0);
}
__device__ __forceinline__ f32x4 mfma16(f16x8 a, f16x8 b, f32x4 c) {
    return __builtin_amdgcn_mfma_f32_16x16x32_f16(a, b, c, 0, 0, 0);
}

// ---------------------------------------------------------------------------
// to_f16: fp32 -> f16 elementwise (8 elems/thread).
// ---------------------------------------------------------------------------
__global__ __launch_bounds__(256) void to_f16(
    const float* __restrict__ X, u16* __restrict__ out)
{
    size_t i = ((size_t)blockIdx.x * 256 + threadIdx.x) * 8;
    float4 a = *(const float4*)(X + i);
    float4 b = *(const float4*)(X + i + 4);
    ushort4 r0, r1;
    r0.x = f2h(a.x); r0.y = f2h(a.y); r0.z = f2h(a.z); r0.w = f2h(a.w);
    r1.x = f2h(b.x); r1.y = f2h(b.y); r1.z = f2h(b.z); r1.w = f2h(b.w);
    *(ushort4*)(out + i)     = r0;
    *(ushort4*)(out + i + 4) = r1;
}

// ---------------------------------------------------------------------------
// transpose_f16: in [Z][R][C] fp32 -> out [Z][C][R] f16. 64x64 LDS tiles.
// ---------------------------------------------------------------------------
__global__ __launch_bounds__(256) void transpose_f16(
    const float* __restrict__ in, u16* __restrict__ out, int R, int C)
{
    __shared__ __align__(16) u16 T[64 * 80];
    const int c0 = blockIdx.x * 64, r0 = blockIdx.y * 64, z = blockIdx.z;
    const int t = threadIdx.x;
    const int rl = t >> 4, c4 = (t & 15) * 4;
    const float* base = in + (size_t)z * R * C;

    #pragma unroll
    for (int rr = 0; rr < 4; ++rr) {
        int r = rr * 16 + rl;
        float4 v = *(const float4*)(base + (size_t)(r0 + r) * C + c0 + c4);
        T[(c4 + 0) * 80 + r] = f2h(v.x);
        T[(c4 + 1) * 80 + r] = f2h(v.y);
        T[(c4 + 2) * 80 + r] = f2h(v.z);
        T[(c4 + 3) * 80 + r] = f2h(v.w);
    }
    __syncthreads();
    #pragma unroll
    for (int rep = 0; rep < 2; ++rep) {
        int idx = rep * 256 + t;
        int cl = idx >> 3, r8 = (idx & 7) * 8;
        *(float4*)(out + ((size_t)z * C + c0 + cl) * R + r0 + r8) =
            *(const float4*)&T[cl * 80 + r8];
    }
}

// ---------------------------------------------------------------------------
// transpose16: in [Z=16][512][4096] f16 -> out [Z][4096][512] f16.
// 64x64 tiles through padded LDS.
// ---------------------------------------------------------------------------
__global__ __launch_bounds__(256) void transpose16(
    const u16* __restrict__ in, u16* __restrict__ out)
{
    __shared__ __align__(16) u16 T[64 * 80];
    const int c0 = blockIdx.x * 64, r0 = blockIdx.y * 64, z = blockIdx.z;
    const int t = threadIdx.x;
    const int rl = t >> 3;          // 0..31
    const int c8 = (t & 7) * 8;     // col chunk base
    const u16* base = in + (size_t)z * 512 * 4096;

    #pragma unroll
    for (int rr = 0; rr < 2; ++rr) {
        int r = rr * 32 + rl;
        const u16* p = base + (size_t)(r0 + r) * 4096 + c0 + c8;
        ushort4 v0 = *(const ushort4*)(p);
        ushort4 v1 = *(const ushort4*)(p + 4);
        T[(c8 + 0) * 80 + r] = v0.x;
        T[(c8 + 1) * 80 + r] = v0.y;
        T[(c8 + 2) * 80 + r] = v0.z;
        T[(c8 + 3) * 80 + r] = v0.w;
        T[(c8 + 4) * 80 + r] = v1.x;
        T[(c8 + 5) * 80 + r] = v1.y;
        T[(c8 + 6) * 80 + r] = v1.z;
        T[(c8 + 7) * 80 + r] = v1.w;
    }
    __syncthreads();
    #pragma unroll
    for (int rep = 0; rep < 2; ++rep) {
        int idx = rep * 256 + t;
        int cl = idx >> 3, r8 = (idx & 7) * 8;
        *(float4*)(out + ((size_t)z * 4096 + c0 + cl) * 512 + r0 + r8) =
            *(const float4*)&T[cl * 80 + r8];
    }
}

// ---------------------------------------------------------------------------
// qkv_mfma: Xh[65536,512](f16) @ WT(f16) + b.  256x256 tile, BK=32, 8 waves
// (2x4, per-wave 128x64), 16x16x32 f16 MFMA.  Per barrier interval: 256 MFMA
// (~1240 CU-cycles) >> load latency, so the 2-phase stage-ahead double buffer
// actually hides the staged loads (round-5's 128-tile had only ~300 cyc of
// compute -> latency-bound at 18% MfmaUtil).
// LDS: 2 buf x (A 16K + B 16K) = 64 KB.  XCD swizzle: 192 blocks/XCD =
// 32 mt x 6 nt (bijective), ~3 MB working set per XCD L2.
// nt 0-3 -> Q/K [bh][n][d]; nt 4-5 -> V transposed into Vt [bh][d][n] via
// per-head LDS tile.
// ---------------------------------------------------------------------------
__global__ __launch_bounds__(512) void qkv_mfma(
    const u16* __restrict__ Xh, const u16* __restrict__ WT,
    const float* __restrict__ bias,
    u16* __restrict__ Q, u16* __restrict__ Kk, u16* __restrict__ Vt)
{
    __shared__ __align__(16) char smem[65536];   // 2 x (As 16K + Bs 16K); Trt[64][272] u16 aliases

    const int id  = blockIdx.x;                  // 0..1535
    const int xcd = id & 7;
    const int jj  = id >> 3;                     // 0..191
    const int mt  = xcd * 32 + jj / 6;           // 0..255
    const int nt  = jj % 6;                      // 0..5

    const int t = threadIdx.x;
    const int wave = t >> 6, lane = t & 63;
    const int wm = wave & 1, wn = wave >> 1;     // 2x4 wave grid: 128 rows x 64 cols each
    const int quad = lane >> 4, l16 = lane & 15;
    const int m0 = mt * 256;

    // staging: rep p in {0,1}: chunk c = p*512 + t; oct = p*2 + (wave>>2),
    // row = (wave&3)*64 + lane.  LDS chunk layout [oct(4)][row(256)] x 16B.
    const int srow = (wave & 3) * 64 + lane;
    size_t xoff[2], woff[2];
    int lb[2];
    #pragma unroll
    for (int p = 0; p < 2; ++p) {
        const int oct = p * 2 + (wave >> 2);
        xoff[p] = (size_t)(m0 + srow) * 512 + oct * 8;
        woff[p] = (size_t)(nt * 256 + srow) * 512 + oct * 8;
        lb[p]   = (p * 512 + wave * 64) * 16;
    }

    f32x4 acc[8][4];
    #pragma unroll
    for (int i = 0; i < 8; ++i)
        #pragma unroll
        for (int j = 0; j < 4; ++j) acc[i][j] = (f32x4){0.f, 0.f, 0.f, 0.f};

    // prologue: stage k0=0 into buffer 0
    #pragma unroll
    for (int p = 0; p < 2; ++p) {
        glds16(Xh + xoff[p], smem + lb[p]);
        glds16(WT + woff[p], smem + 16384 + lb[p]);
    }
    __syncthreads();

    for (int k0 = 0; k0 < 512; k0 += 32) {
        const int co = (k0 & 32) << 10;          // alternates 0 / 32768
        const int cn = co ^ 32768;
        char* Ac = smem + co;
        char* Bc = smem + co + 16384;
        if (k0 < 480) {                          // stage NEXT chunk before compute
            #pragma unroll
            for (int p = 0; p < 2; ++p) {
                glds16(Xh + xoff[p] + k0 + 32, smem + cn + lb[p]);
                glds16(WT + woff[p] + k0 + 32, smem + cn + 16384 + lb[p]);
            }
        }

        f16x8 af[8], bf[4];
        #pragma unroll
        for (int i = 0; i < 8; ++i)
            af[i] = *(const f16x8*)(Ac + (quad * 256 + wm * 128 + i * 16 + l16) * 16);
        #pragma unroll
        for (int j = 0; j < 4; ++j)
            bf[j] = *(const f16x8*)(Bc + (quad * 256 + wn * 64 + j * 16 + l16) * 16);
        #pragma unroll
        for (int i = 0; i < 8; ++i)
            #pragma unroll
            for (int j = 0; j < 4; ++j)
                acc[i][j] = mfma16(af[i], bf[j], acc[i][j]);

        __syncthreads();   // drains next-chunk loads (after ~1240cyc compute) + WAR
    }

    const int b   = m0 >> 12;
    const int nn0 = m0 & 4095;
    float bv[4];
    #pragma unroll
    for (int j = 0; j < 4; ++j) bv[j] = bias[nt * 256 + wn * 64 + j * 16 + l16];

    if (nt < 4) {
        u16* dst = (nt < 2) ? Q : Kk;
        const int colbase = (nt & 1) * 256;
        #pragma unroll
        for (int i = 0; i < 8; ++i) {
            const int rowb = wm * 128 + i * 16 + quad * 4;
            #pragma unroll
            for (int j = 0; j < 4; ++j) {
                const int col = colbase + wn * 64 + j * 16 + l16;
                const int h = col >> 6, d = col & 63;
                u16* p = dst + ((size_t)((b * 8 + h) * 4096 + nn0 + rowb)) * 64 + d;
                #pragma unroll
                for (int r = 0; r < 4; ++r)
                    p[(size_t)r * 64] = f2h(acc[i][j][r] + bv[j]);
            }
        }
    } else {
        // V: per head-group g (=wn of owning waves), transpose 256n x 64d
        // through Trt[64][272] u16, then coalesced 16B writes to Vt.
        u16* Trt = (u16*)smem;                   // [64][272], 34816 B
        const int hb = (nt - 4) * 4;
        #pragma unroll
        for (int g = 0; g < 4; ++g) {
            __syncthreads();                     // WAR vs previous copy / K-loop
            if (wn == g) {
                #pragma unroll
                for (int i = 0; i < 8; ++i)
                    #pragma unroll
                    for (int j = 0; j < 4; ++j)
                        #pragma unroll
                        for (int r = 0; r < 4; ++r)
                            Trt[(j * 16 + l16) * 272 + wm * 128 + i * 16 + quad * 4 + r] =
                                f2h(acc[i][j][r] + bv[j]);
            }
            __syncthreads();
            const int h = hb + g;
            u16* dstv = Vt + ((size_t)(b * 8 + h) * 64) * 4096 + nn0;
            #pragma unroll
            for (int rep = 0; rep < 4; ++rep) {
                int idx = rep * 512 + t;
                int d = idx >> 5, r8 = (idx & 31) * 8;
                *(float4*)(dstv + (size_t)d * 4096 + r8) =
                    *(const float4*)&Trt[d * 272 + r8];
            }
        }
    }
}

// ---------------------------------------------------------------------------
// attn_logits (MFMA, no-LDS main loop): f16 Q,K in, fp32 softmaxed logits out.
// ---------------------------------------------------------------------------
__global__ __launch_bounds__(256) void attn_logits(
    const u16* __restrict__ Q, const u16* __restrict__ Kk,
    float* __restrict__ Aout, float* __restrict__ Bmout)
{
    __shared__ float sm[64 * 68];
    __shared__ float red[128];

    const int bh   = blockIdx.x;
    const int mode = blockIdx.y;
    const int t    = threadIdx.x;
    const int wave = t >> 6, lane = t & 63;
    const int wr = wave & 1, wc = wave >> 1;     // 2x2 wave grid, 32x32 per wave
    const int quad = lane >> 4, l16 = lane & 15;

    const u16* Qb = Q  + (size_t)bh * 262144;
    const u16* Kb = Kk + (size_t)bh * 262144;

    const int rA0 = wr * 32 + l16, rA1 = rA0 + 16;   // A rows (Q)
    const int rB0 = wc * 32 + l16, rB1 = rB0 + 16;   // B rows (K)

    f32x4 acc[2][2];
    #pragma unroll
    for (int i = 0; i < 2; ++i)
        #pragma unroll
        for (int j = 0; j < 2; ++j) acc[i][j] = (f32x4){0.f, 0.f, 0.f, 0.f};

    if (mode == 0) {
        const u16* pA0 = Qb + (size_t)rA0 * 4096;
        const u16* pA1 = Qb + (size_t)rA1 * 4096;
        const u16* pB0 = Kb + (size_t)rB0 * 4096;
        const u16* pB1 = Kb + (size_t)rB1 * 4096;
        #pragma unroll 4
        for (int k0 = 0; k0 < 4096; k0 += 32) {
            const int kk = k0 + quad * 8;
            f16x8 a0 = *(const f16x8*)(pA0 + kk);
            f16x8 a1 = *(const f16x8*)(pA1 + kk);
            f16x8 b0 = *(const f16x8*)(pB0 + kk);
            f16x8 b1 = *(const f16x8*)(pB1 + kk);
            acc[0][0] = mfma16(a0, b0, acc[0][0]);
            acc[0][1] = mfma16(a0, b1, acc[0][1]);
            acc[1][0] = mfma16(a1, b0, acc[1][0]);
            acc[1][1] = mfma16(a1, b1, acc[1][1]);
        }
    } else {
        #pragma unroll 4
        for (int k0 = 0; k0 < 4096; k0 += 32) {
            const int kk = k0 + quad * 8;
            const size_t base = (size_t)(kk >> 6) * 4096 + (kk & 63);
            f16x8 a0 = *(const f16x8*)(Qb + base + rA0 * 64);
            f16x8 a1 = *(const f16x8*)(Qb + base + rA1 * 64);
            f16x8 b0 = *(const f16x8*)(Kb + base + rB0 * 64);
            f16x8 b1 = *(const f16x8*)(Kb + base + rB1 * 64);
            acc[0][0] = mfma16(a0, b0, acc[0][0]);
            acc[0][1] = mfma16(a0, b1, acc[0][1]);
            acc[1][0] = mfma16(a1, b0, acc[1][0]);
            acc[1][1] = mfma16(a1, b1, acc[1][1]);
        }
    }

    #pragma unroll
    for (int i = 0; i < 2; ++i)
        #pragma unroll
        for (int j = 0; j < 2; ++j)
            #pragma unroll
            for (int r = 0; r < 4; ++r)
                sm[(wr * 32 + i * 16 + quad * 4 + r) * 68 + wc * 32 + j * 16 + l16] =
                    acc[i][j][r] * SCALE_F;
    __syncthreads();
    if (t < 64) {
        float m = -1e30f;
        for (int j = 0; j < 64; ++j) m = fmaxf(m, sm[t * 68 + j]);
        float ssum = 0.f;
        for (int j = 0; j < 64; ++j) ssum += __expf(sm[t * 68 + j] - m);
        red[t] = m;
        red[64 + t] = 1.0f / ssum;
    }
    __syncthreads();
    float* Out = ((mode == 0) ? Aout : Bmout) + (size_t)bh * 4096;
    #pragma unroll
    for (int rep = 0; rep < 16; ++rep) {
        int idx = rep * 256 + t;
        int i = idx >> 6, j = idx & 63;
        Out[idx] = __expf(sm[i * 68 + j] - red[i]) * red[64 + i];
    }
}

// ---------------------------------------------------------------------------
// coupling (MFMA): per (bh,c): out_c = A · (V_c · Bm^T).
//   GEMM1: tmpT[u][j] = sum_w Bm[u][w] * Vc[j][w]   (V rows direct from global)
//   GEMM2: out[i][u]  = sum_j A[i][j] * tmpT[u][j]
// A,Bm converted fp32->f16 into LDS once per block; tmpT double-buffered in
// LDS (one barrier per c).  Output f16 [bh][c][n], n = i*64 + u.
// 4 waves 2x2 (32x32 tile each), 16 c per block.
// ---------------------------------------------------------------------------
__global__ __launch_bounds__(256) void coupling(
    const u16* __restrict__ Vt, const float* __restrict__ Aatt,
    const float* __restrict__ Bm, u16* __restrict__ Yh)
{
    __shared__ __align__(16) u16 Ah[64 * 72];
    __shared__ __align__(16) u16 Bh[64 * 72];
    __shared__ __align__(16) u16 Tt[2][64 * 72];

    const int bh = blockIdx.x, cg = blockIdx.y;
    const int t = threadIdx.x;
    const int wave = t >> 6, lane = t & 63;
    const int wr = wave & 1, wc = wave >> 1;
    const int quad = lane >> 4, l16 = lane & 15;

    const float* Ab = Aatt + (size_t)bh * 4096;
    const float* Bb = Bm   + (size_t)bh * 4096;
    const u16*  Vb  = Vt   + (size_t)bh * 262144;
    u16* Yb = Yh + (size_t)bh * 262144;

    {   // A[i][j], Bm[u][w] -> f16 LDS row-major stride 72
        const int row = t >> 2;
        const int colb = (t & 3) * 16;
        #pragma unroll
        for (int q = 0; q < 4; ++q) {
            float4 va = *(const float4*)(Ab + (size_t)row * 64 + colb + q * 4);
            Ah[row * 72 + colb + q * 4 + 0] = f2h(va.x);
            Ah[row * 72 + colb + q * 4 + 1] = f2h(va.y);
            Ah[row * 72 + colb + q * 4 + 2] = f2h(va.z);
            Ah[row * 72 + colb + q * 4 + 3] = f2h(va.w);
            float4 vb = *(const float4*)(Bb + (size_t)row * 64 + colb + q * 4);
            Bh[row * 72 + colb + q * 4 + 0] = f2h(vb.x);
            Bh[row * 72 + colb + q * 4 + 1] = f2h(vb.y);
            Bh[row * 72 + colb + q * 4 + 2] = f2h(vb.z);
            Bh[row * 72 + colb + q * 4 + 3] = f2h(vb.w);
        }
    }
    __syncthreads();

    for (int ci = 0; ci < 16; ++ci) {
        const int c = cg * 16 + ci;
        u16* tb = &Tt[ci & 1][0];

        // GEMM1: rows u (from Bh), cols j (V rows from global), K = w (64)
        f32x4 acc1[2][2];
        #pragma unroll
        for (int i = 0; i < 2; ++i)
            #pragma unroll
            for (int j = 0; j < 2; ++j) acc1[i][j] = (f32x4){0.f, 0.f, 0.f, 0.f};
        #pragma unroll
        for (int s = 0; s < 2; ++s) {
            f16x8 a1[2], b1[2];
            #pragma unroll
            for (int i = 0; i < 2; ++i)
                a1[i] = *(const f16x8*)&Bh[(wr * 32 + i * 16 + l16) * 72 + s * 32 + quad * 8];
            #pragma unroll
            for (int j = 0; j < 2; ++j)
                b1[j] = *(const f16x8*)(Vb + (size_t)c * 4096 +
                                        (size_t)(wc * 32 + j * 16 + l16) * 64 + s * 32 + quad * 8);
            #pragma unroll
            for (int i = 0; i < 2; ++i)
                #pragma unroll
                for (int j = 0; j < 2; ++j)
                    acc1[i][j] = mfma16(a1[i], b1[j], acc1[i][j]);
        }
        // store tmpT[u][j] as f16
        #pragma unroll
        for (int i = 0; i < 2; ++i)
            #pragma unroll
            for (int j = 0; j < 2; ++j)
                #pragma unroll
                for (int r = 0; r < 4; ++r)
                    tb[(wr * 32 + i * 16 + quad * 4 + r) * 72 + wc * 32 + j * 16 + l16] =
                        f2h(acc1[i][j][r]);
        __syncthreads();

        // GEMM2: rows i (from Ah), cols u (tmpT rows), K = j (64)
        f32x4 acc2[2][2];
        #pragma unroll
        for (int i = 0; i < 2; ++i)
            #pragma unroll
            for (int j = 0; j < 2; ++j) acc2[i][j] = (f32x4){0.f, 0.f, 0.f, 0.f};
        #pragma unroll
        for (int s = 0; s < 2; ++s) {
            f16x8 a2[2], b2[2];
            #pragma unroll
            for (int i = 0; i < 2; ++i)
                a2[i] = *(const f16x8*)&Ah[(wr * 32 + i * 16 + l16) * 72 + s * 32 + quad * 8];
            #pragma unroll
            for (int u = 0; u < 2; ++u)
                b2[u] = *(const f16x8*)&tb[(wc * 32 + u * 16 + l16) * 72 + s * 32 + quad * 8];
            #pragma unroll
            for (int i = 0; i < 2; ++i)
                #pragma unroll
                for (int u = 0; u < 2; ++u)
                    acc2[i][u] = mfma16(a2[i], b2[u], acc2[i][u]);
        }
        // out[i][u] -> Yh[bh][c][i*64+u] f16
        #pragma unroll
        for (int i = 0; i < 2; ++i)
            #pragma unroll
            for (int u = 0; u < 2; ++u)
                #pragma unroll
                for (int r = 0; r < 4; ++r)
                    Yb[(size_t)c * 4096 + (wr * 32 + i * 16 + quad * 4 + r) * 64 +
                       wc * 32 + u * 16 + l16] = f2h(acc2[i][u][r]);
    }
}

// ---------------------------------------------------------------------------
// proj_mfma: Ytb[65536,512](f16) @ WpT(f16) + b -> Out fp32 [65536,512].
// BK=32, double-buffered stage-ahead (same schedule as qkv_mfma), XCD swizzle.
// ---------------------------------------------------------------------------
__global__ __launch_bounds__(256) void proj_mfma(
    const u16* __restrict__ A, const u16* __restrict__ WT,
    const float* __restrict__ bias, float* __restrict__ Out)
{
    __shared__ __align__(16) char smem[32768];   // 2x(As 8K + Bs 8K)

    const int id  = blockIdx.x;                  // 0..2047
    const int xcd = id & 7;
    const int jj  = id >> 3;                     // 0..255
    const int mt  = xcd * 64 + (jj >> 2);
    const int nt  = jj & 3;

    const int t = threadIdx.x;
    const int wave = t >> 6, lane = t & 63;
    const int wm = wave & 1, wn = wave >> 1;
    const int quad = lane >> 4, l16 = lane & 15;
    const int m0 = mt * 128;

    const int c0 = wave * 128 + lane;
    const int c1 = c0 + 64;
    const size_t aoff0 = (size_t)(m0 + (c0 & 127)) * 512 + (c0 >> 7) * 8;
    const size_t aoff1 = (size_t)(m0 + (c1 & 127)) * 512 + (c1 >> 7) * 8;
    const size_t woff0 = (size_t)(nt * 128 + (c0 & 127)) * 512 + (c0 >> 7) * 8;
    const size_t woff1 = (size_t)(nt * 128 + (c1 & 127)) * 512 + (c1 >> 7) * 8;
    const int lb0 = (wave * 128) * 16;
    const int lb1 = lb0 + 64 * 16;

    f32x4 acc[4][4];
    #pragma unroll
    for (int i = 0; i < 4; ++i)
        #pragma unroll
        for (int j = 0; j < 4; ++j) acc[i][j] = (f32x4){0.f, 0.f, 0.f, 0.f};

    glds16(A  + aoff0, smem + lb0);
    glds16(A  + aoff1, smem + lb1);
    glds16(WT + woff0, smem + 8192 + lb0);
    glds16(WT + woff1, smem + 8192 + lb1);
    __syncthreads();

    for (int k0 = 0; k0 < 512; k0 += 32) {
        const int co = (k0 & 32) << 9;
        const int cn = co ^ 16384;
        char* Ac = smem + co;
        char* Bc = smem + 8192 + co;
        if (k0 < 480) {
            glds16(A  + aoff0 + k0 + 32, smem + cn + lb0);
            glds16(A  + aoff1 + k0 + 32, smem + cn + lb1);
            glds16(WT + woff0 + k0 + 32, smem + 8192 + cn + lb0);
            glds16(WT + woff1 + k0 + 32, smem + 8192 + cn + lb1);
        }

        f16x8 af[4], bf[4];
        #pragma unroll
        for (int i = 0; i < 4; ++i)
            af[i] = *(const f16x8*)(Ac + (quad * 128 + wm * 64 + i * 16 + l16) * 16);
        #pragma unroll
        for (int j = 0; j < 4; ++j)
            bf[j] = *(const f16x8*)(Bc + (quad * 128 + wn * 64 + j * 16 + l16) * 16);
        #pragma unroll
        for (int i = 0; i < 4; ++i)
            #pragma unroll
            for (int j = 0; j < 4; ++j)
                acc[i][j] = mfma16(af[i], bf[j], acc[i][j]);

        __syncthreads();
    }

    float bv[4];
    #pragma unroll
    for (int j = 0; j < 4; ++j) bv[j] = bias[nt * 128 + wn * 64 + j * 16 + l16];

    #pragma unroll
    for (int i = 0; i < 4; ++i) {
        const int rowb = m0 + wm * 64 + i * 16 + quad * 4;
        #pragma unroll
        for (int j = 0; j < 4; ++j) {
            const int col = nt * 128 + wn * 64 + j * 16 + l16;
            #pragma unroll
            for (int r = 0; r < 4; ++r)
                Out[(size_t)(rowb + r) * 512 + col] = acc[i][j][r] + bv[j];
        }
    }
}

// ---------------------------------------------------------------------------
extern "C" void kernel_launch(void* const* d_in, const int* in_sizes, int n_in,
                              void* d_out, int out_size, void* d_ws, size_t ws_size,
                              hipStream_t stream)
{
    const float* x     = (const float*)d_in[0];
    const float* Wqkv  = (const float*)d_in[1];
    const float* bqkv  = (const float*)d_in[2];
    const float* Wproj = (const float*)d_in[3];
    const float* bproj = (const float*)d_in[4];
    float* out = (float*)d_out;

    u16* Xh  = (u16*)d_ws;                  // 33554432 elems (64 MB)
    u16* Qh  = Xh + 33554432;
    u16* Kh  = Qh + 33554432;
    u16* Vth = Kh + 33554432;
    u16* WqT = Vth + 33554432;              // 786432
    u16* WpT = WqT + 786432;                // 262144
    float* Aa = (float*)(WpT + 262144);     // 524288 f
    float* Bm = Aa + 524288;                // 524288 f
    u16* Yh  = Xh;                          // 64 MB f16, aliases Xh (dead after qkv)
    u16* Ytb = Kh;                          // aliases Kh (dead after attn)

    to_f16        <<<16384, 256, 0, stream>>>(x, Xh);
    transpose_f16 <<<dim3(24, 8, 1),  256, 0, stream>>>(Wqkv,  WqT, 512, 1536);
    transpose_f16 <<<dim3(8, 8, 1),   256, 0, stream>>>(Wproj, WpT, 512, 512);
    qkv_mfma      <<<1536,            512, 0, stream>>>(Xh, WqT, bqkv, Qh, Kh, Vth);
    attn_logits   <<<dim3(128, 2),    256, 0, stream>>>(Qh, Kh, Aa, Bm);
    coupling      <<<dim3(128, 4),    256, 0, stream>>>(Vth, Aa, Bm, Yh);
    transpose16   <<<dim3(64, 8, 16), 256, 0, stream>>>(Yh, Ytb);
    proj_mfma     <<<2048,            256, 0, stream>>>(Ytb, WpT, bproj, out);
}

// Round 7
// 648.541 us; speedup vs baseline: 1.2506x; 1.0231x over previous
//
#include <hip/hip_runtime.h>
#include <math.h>

#define SCALE_F 0.35355339059327373f   // 64^-0.25

typedef unsigned short u16;
typedef unsigned int   u32;
typedef _Float16 f16;
typedef _Float16 f16x8 __attribute__((ext_vector_type(8)));
typedef float    f32x4 __attribute__((ext_vector_type(4)));

__device__ __forceinline__ u16 f2h(float f) { f16 h = (f16)f; return *(u16*)&h; }
__device__ __forceinline__ float h2f(u16 b) { f16 h = *(f16*)&b; return (float)h; }

__device__ __forceinline__ void glds16(const u16* g, char* l) {
    __builtin_amdgcn_global_load_lds((const __attribute__((address_space(1))) void*)g,
                                     (__attribute__((address_space(3))) void*)l, 16, 0, 0);
}
__device__ __forceinline__ f32x4 mfma16(f16x8 a, f16x8 b, f32x4 c) {
    return __builtin_amdgcn_mfma_f32_16x16x32_f16(a, b, c, 0, 0, 0);
}

// ---------------------------------------------------------------------------
// to_f16: fp32 -> f16 elementwise (8 elems/thread).
// ---------------------------------------------------------------------------
__global__ __launch_bounds__(256) void to_f16(
    const float* __restrict__ X, u16* __restrict__ out)
{
    size_t i = ((size_t)blockIdx.x * 256 + threadIdx.x) * 8;
    float4 a = *(const float4*)(X + i);
    float4 b = *(const float4*)(X + i + 4);
    ushort4 r0, r1;
    r0.x = f2h(a.x); r0.y = f2h(a.y); r0.z = f2h(a.z); r0.w = f2h(a.w);
    r1.x = f2h(b.x); r1.y = f2h(b.y); r1.z = f2h(b.z); r1.w = f2h(b.w);
    *(ushort4*)(out + i)     = r0;
    *(ushort4*)(out + i + 4) = r1;
}

// ---------------------------------------------------------------------------
// transpose_f16: in [Z][R][C] fp32 -> out [Z][C][R] f16. 64x64 LDS tiles.
// ---------------------------------------------------------------------------
__global__ __launch_bounds__(256) void transpose_f16(
    const float* __restrict__ in, u16* __restrict__ out, int R, int C)
{
    __shared__ __align__(16) u16 T[64 * 80];
    const int c0 = blockIdx.x * 64, r0 = blockIdx.y * 64, z = blockIdx.z;
    const int t = threadIdx.x;
    const int rl = t >> 4, c4 = (t & 15) * 4;
    const float* base = in + (size_t)z * R * C;

    #pragma unroll
    for (int rr = 0; rr < 4; ++rr) {
        int r = rr * 16 + rl;
        float4 v = *(const float4*)(base + (size_t)(r0 + r) * C + c0 + c4);
        T[(c4 + 0) * 80 + r] = f2h(v.x);
        T[(c4 + 1) * 80 + r] = f2h(v.y);
        T[(c4 + 2) * 80 + r] = f2h(v.z);
        T[(c4 + 3) * 80 + r] = f2h(v.w);
    }
    __syncthreads();
    #pragma unroll
    for (int rep = 0; rep < 2; ++rep) {
        int idx = rep * 256 + t;
        int cl = idx >> 3, r8 = (idx & 7) * 8;
        *(float4*)(out + ((size_t)z * C + c0 + cl) * R + r0 + r8) =
            *(const float4*)&T[cl * 80 + r8];
    }
}

// ---------------------------------------------------------------------------
// transpose16: in [Z=16][512][4096] f16 -> out [Z][4096][512] f16.
// 64x64 tiles through padded LDS.
// ---------------------------------------------------------------------------
__global__ __launch_bounds__(256) void transpose16(
    const u16* __restrict__ in, u16* __restrict__ out)
{
    __shared__ __align__(16) u16 T[64 * 80];
    const int c0 = blockIdx.x * 64, r0 = blockIdx.y * 64, z = blockIdx.z;
    const int t = threadIdx.x;
    const int rl = t >> 3;          // 0..31
    const int c8 = (t & 7) * 8;     // col chunk base
    const u16* base = in + (size_t)z * 512 * 4096;

    #pragma unroll
    for (int rr = 0; rr < 2; ++rr) {
        int r = rr * 32 + rl;
        const u16* p = base + (size_t)(r0 + r) * 4096 + c0 + c8;
        ushort4 v0 = *(const ushort4*)(p);
        ushort4 v1 = *(const ushort4*)(p + 4);
        T[(c8 + 0) * 80 + r] = v0.x;
        T[(c8 + 1) * 80 + r] = v0.y;
        T[(c8 + 2) * 80 + r] = v0.z;
        T[(c8 + 3) * 80 + r] = v0.w;
        T[(c8 + 4) * 80 + r] = v1.x;
        T[(c8 + 5) * 80 + r] = v1.y;
        T[(c8 + 6) * 80 + r] = v1.z;
        T[(c8 + 7) * 80 + r] = v1.w;
    }
    __syncthreads();
    #pragma unroll
    for (int rep = 0; rep < 2; ++rep) {
        int idx = rep * 256 + t;
        int cl = idx >> 3, r8 = (idx & 7) * 8;
        *(float4*)(out + ((size_t)z * 4096 + c0 + cl) * 512 + r0 + r8) =
            *(const float4*)&T[cl * 80 + r8];
    }
}

// ---------------------------------------------------------------------------
// qkv_mfma: Xh[65536,512](f16) @ WT(f16) + b.  256x256 tile, BK=32, 8 waves
// (2x4, per-wave 128x64), 16x16x32 f16 MFMA, 2-phase stage-ahead dbuf.
// EPILOGUE (round-7): Q/K writes were scalar u16 at 32-B runs -> write-bound
// at ~1.2 TB/s (r6 counters).  Now: per-wave 8KB LDS transpose with XOR
// swizzle (byte ^= (row&7)<<4, same involution both sides) -> float4 stores,
// 1 KB contiguous per wave-store.  No barriers needed (wave-private region,
// smem dead after K-loop).
// nt 0-3 -> Q/K [bh][n][d]; nt 4-5 -> V transposed into Vt [bh][d][n].
// ---------------------------------------------------------------------------
__global__ __launch_bounds__(512) void qkv_mfma(
    const u16* __restrict__ Xh, const u16* __restrict__ WT,
    const float* __restrict__ bias,
    u16* __restrict__ Q, u16* __restrict__ Kk, u16* __restrict__ Vt)
{
    __shared__ __align__(16) char smem[65536];   // 2 x (As 16K + Bs 16K); epilogue aliases

    const int id  = blockIdx.x;                  // 0..1535
    const int xcd = id & 7;
    const int jj  = id >> 3;                     // 0..191
    const int mt  = xcd * 32 + jj / 6;           // 0..255
    const int nt  = jj % 6;                      // 0..5

    const int t = threadIdx.x;
    const int wave = t >> 6, lane = t & 63;
    const int wm = wave & 1, wn = wave >> 1;     // 2x4 wave grid: 128 rows x 64 cols each
    const int quad = lane >> 4, l16 = lane & 15;
    const int m0 = mt * 256;

    const int srow = (wave & 3) * 64 + lane;
    size_t xoff[2], woff[2];
    int lb[2];
    #pragma unroll
    for (int p = 0; p < 2; ++p) {
        const int oct = p * 2 + (wave >> 2);
        xoff[p] = (size_t)(m0 + srow) * 512 + oct * 8;
        woff[p] = (size_t)(nt * 256 + srow) * 512 + oct * 8;
        lb[p]   = (p * 512 + wave * 64) * 16;
    }

    f32x4 acc[8][4];
    #pragma unroll
    for (int i = 0; i < 8; ++i)
        #pragma unroll
        for (int j = 0; j < 4; ++j) acc[i][j] = (f32x4){0.f, 0.f, 0.f, 0.f};

    #pragma unroll
    for (int p = 0; p < 2; ++p) {
        glds16(Xh + xoff[p], smem + lb[p]);
        glds16(WT + woff[p], smem + 16384 + lb[p]);
    }
    __syncthreads();

    for (int k0 = 0; k0 < 512; k0 += 32) {
        const int co = (k0 & 32) << 10;          // alternates 0 / 32768
        const int cn = co ^ 32768;
        char* Ac = smem + co;
        char* Bc = smem + co + 16384;
        if (k0 < 480) {
            #pragma unroll
            for (int p = 0; p < 2; ++p) {
                glds16(Xh + xoff[p] + k0 + 32, smem + cn + lb[p]);
                glds16(WT + woff[p] + k0 + 32, smem + cn + 16384 + lb[p]);
            }
        }

        f16x8 af[8], bf[4];
        #pragma unroll
        for (int i = 0; i < 8; ++i)
            af[i] = *(const f16x8*)(Ac + (quad * 256 + wm * 128 + i * 16 + l16) * 16);
        #pragma unroll
        for (int j = 0; j < 4; ++j)
            bf[j] = *(const f16x8*)(Bc + (quad * 256 + wn * 64 + j * 16 + l16) * 16);
        #pragma unroll
        for (int i = 0; i < 8; ++i)
            #pragma unroll
            for (int j = 0; j < 4; ++j)
                acc[i][j] = mfma16(af[i], bf[j], acc[i][j]);

        __syncthreads();
    }

    const int b   = m0 >> 12;
    const int nn0 = m0 & 4095;
    float bv[4];
    #pragma unroll
    for (int j = 0; j < 4; ++j) bv[j] = bias[nt * 256 + wn * 64 + j * 16 + l16];

    if (nt < 4) {
        // per-wave LDS transpose -> coalesced float4 stores (no barriers:
        // wave-private 8KB region; all waves passed the K-loop's last barrier)
        u16* dst = (nt < 2) ? Q : Kk;
        const int hh = (nt & 1) * 4 + wn;        // this wave's head
        char* Tw = smem + wave * 8192;           // [64 rows][128 B], XOR-swizzled
        u16* dsth = dst + ((size_t)(b * 8 + hh) * 4096 + nn0 + wm * 128) * 64;
        const int r8 = lane >> 3, l8 = lane & 7;
        #pragma unroll
        for (int g = 0; g < 2; ++g) {
            #pragma unroll
            for (int i2 = 0; i2 < 4; ++i2) {
                const int i = g * 4 + i2;
                #pragma unroll
                for (int j = 0; j < 4; ++j) {
                    #pragma unroll
                    for (int r = 0; r < 4; ++r) {
                        const int rl = i2 * 16 + quad * 4 + r;       // 0..63
                        const int cb = (j * 16 + l16) * 2;           // byte col
                        *(u16*)(Tw + rl * 128 + (cb ^ ((rl & 7) << 4))) =
                            f2h(acc[i][j][r] + bv[j]);
                    }
                }
            }
            #pragma unroll
            for (int rep = 0; rep < 8; ++rep) {
                const int rl = rep * 8 + r8;                          // 0..63
                f16x8 v = *(const f16x8*)(Tw + rl * 128 + ((l8 * 16) ^ ((rl & 7) << 4)));
                *(float4*)(dsth + (size_t)(g * 64 + rl) * 64 + l8 * 8) = *(float4*)&v;
            }
        }
    } else {
        // V: per head-group g (=wn of owning waves), transpose 256n x 64d
        // through Trt[64][272] u16, then coalesced 16B writes to Vt.
        u16* Trt = (u16*)smem;                   // [64][272], 34816 B
        const int hb = (nt - 4) * 4;
        #pragma unroll
        for (int g = 0; g < 4; ++g) {
            __syncthreads();                     // WAR vs previous copy / K-loop
            if (wn == g) {
                #pragma unroll
                for (int i = 0; i < 8; ++i)
                    #pragma unroll
                    for (int j = 0; j < 4; ++j)
                        #pragma unroll
                        for (int r = 0; r < 4; ++r)
                            Trt[(j * 16 + l16) * 272 + wm * 128 + i * 16 + quad * 4 + r] =
                                f2h(acc[i][j][r] + bv[j]);
            }
            __syncthreads();
            const int h = hb + g;
            u16* dstv = Vt + ((size_t)(b * 8 + h) * 64) * 4096 + nn0;
            #pragma unroll
            for (int rep = 0; rep < 4; ++rep) {
                int idx = rep * 512 + t;
                int d = idx >> 5, r8v = (idx & 31) * 8;
                *(float4*)(dstv + (size_t)d * 4096 + r8v) =
                    *(const float4*)&Trt[d * 272 + r8v];
            }
        }
    }
}

// ---------------------------------------------------------------------------
// attn_logits (MFMA, no-LDS main loop): f16 Q,K in, fp32 softmaxed logits out.
// ---------------------------------------------------------------------------
__global__ __launch_bounds__(256) void attn_logits(
    const u16* __restrict__ Q, const u16* __restrict__ Kk,
    float* __restrict__ Aout, float* __restrict__ Bmout)
{
    __shared__ float sm[64 * 68];
    __shared__ float red[128];

    const int bh   = blockIdx.x;
    const int mode = blockIdx.y;
    const int t    = threadIdx.x;
    const int wave = t >> 6, lane = t & 63;
    const int wr = wave & 1, wc = wave >> 1;     // 2x2 wave grid, 32x32 per wave
    const int quad = lane >> 4, l16 = lane & 15;

    const u16* Qb = Q  + (size_t)bh * 262144;
    const u16* Kb = Kk + (size_t)bh * 262144;

    const int rA0 = wr * 32 + l16, rA1 = rA0 + 16;   // A rows (Q)
    const int rB0 = wc * 32 + l16, rB1 = rB0 + 16;   // B rows (K)

    f32x4 acc[2][2];
    #pragma unroll
    for (int i = 0; i < 2; ++i)
        #pragma unroll
        for (int j = 0; j < 2; ++j) acc[i][j] = (f32x4){0.f, 0.f, 0.f, 0.f};

    if (mode == 0) {
        const u16* pA0 = Qb + (size_t)rA0 * 4096;
        const u16* pA1 = Qb + (size_t)rA1 * 4096;
        const u16* pB0 = Kb + (size_t)rB0 * 4096;
        const u16* pB1 = Kb + (size_t)rB1 * 4096;
        #pragma unroll 4
        for (int k0 = 0; k0 < 4096; k0 += 32) {
            const int kk = k0 + quad * 8;
            f16x8 a0 = *(const f16x8*)(pA0 + kk);
            f16x8 a1 = *(const f16x8*)(pA1 + kk);
            f16x8 b0 = *(const f16x8*)(pB0 + kk);
            f16x8 b1 = *(const f16x8*)(pB1 + kk);
            acc[0][0] = mfma16(a0, b0, acc[0][0]);
            acc[0][1] = mfma16(a0, b1, acc[0][1]);
            acc[1][0] = mfma16(a1, b0, acc[1][0]);
            acc[1][1] = mfma16(a1, b1, acc[1][1]);
        }
    } else {
        #pragma unroll 4
        for (int k0 = 0; k0 < 4096; k0 += 32) {
            const int kk = k0 + quad * 8;
            const size_t base = (size_t)(kk >> 6) * 4096 + (kk & 63);
            f16x8 a0 = *(const f16x8*)(Qb + base + rA0 * 64);
            f16x8 a1 = *(const f16x8*)(Qb + base + rA1 * 64);
            f16x8 b0 = *(const f16x8*)(Kb + base + rB0 * 64);
            f16x8 b1 = *(const f16x8*)(Kb + base + rB1 * 64);
            acc[0][0] = mfma16(a0, b0, acc[0][0]);
            acc[0][1] = mfma16(a0, b1, acc[0][1]);
            acc[1][0] = mfma16(a1, b0, acc[1][0]);
            acc[1][1] = mfma16(a1, b1, acc[1][1]);
        }
    }

    #pragma unroll
    for (int i = 0; i < 2; ++i)
        #pragma unroll
        for (int j = 0; j < 2; ++j)
            #pragma unroll
            for (int r = 0; r < 4; ++r)
                sm[(wr * 32 + i * 16 + quad * 4 + r) * 68 + wc * 32 + j * 16 + l16] =
                    acc[i][j][r] * SCALE_F;
    __syncthreads();
    if (t < 64) {
        float m = -1e30f;
        for (int j = 0; j < 64; ++j) m = fmaxf(m, sm[t * 68 + j]);
        float ssum = 0.f;
        for (int j = 0; j < 64; ++j) ssum += __expf(sm[t * 68 + j] - m);
        red[t] = m;
        red[64 + t] = 1.0f / ssum;
    }
    __syncthreads();
    float* Out = ((mode == 0) ? Aout : Bmout) + (size_t)bh * 4096;
    #pragma unroll
    for (int rep = 0; rep < 16; ++rep) {
        int idx = rep * 256 + t;
        int i = idx >> 6, j = idx & 63;
        Out[idx] = __expf(sm[i * 68 + j] - red[i]) * red[64 + i];
    }
}

// ---------------------------------------------------------------------------
// coupling (MFMA): per (bh,c): out_c = A · (V_c · Bm^T).
// Round-7: output staged through Ot[64][72] -> coalesced float4 row writes
// (was scalar u16 at 32-B runs).
// ---------------------------------------------------------------------------
__global__ __launch_bounds__(256) void coupling(
    const u16* __restrict__ Vt, const float* __restrict__ Aatt,
    const float* __restrict__ Bm, u16* __restrict__ Yh)
{
    __shared__ __align__(16) u16 Ah[64 * 72];
    __shared__ __align__(16) u16 Bh[64 * 72];
    __shared__ __align__(16) u16 Tt[2][64 * 72];
    __shared__ __align__(16) u16 Ot[64 * 72];

    const int bh = blockIdx.x, cg = blockIdx.y;
    const int t = threadIdx.x;
    const int wave = t >> 6, lane = t & 63;
    const int wr = wave & 1, wc = wave >> 1;
    const int quad = lane >> 4, l16 = lane & 15;

    const float* Ab = Aatt + (size_t)bh * 4096;
    const float* Bb = Bm   + (size_t)bh * 4096;
    const u16*  Vb  = Vt   + (size_t)bh * 262144;
    u16* Yb = Yh + (size_t)bh * 262144;

    {   // A[i][j], Bm[u][w] -> f16 LDS row-major stride 72
        const int row = t >> 2;
        const int colb = (t & 3) * 16;
        #pragma unroll
        for (int q = 0; q < 4; ++q) {
            float4 va = *(const float4*)(Ab + (size_t)row * 64 + colb + q * 4);
            Ah[row * 72 + colb + q * 4 + 0] = f2h(va.x);
            Ah[row * 72 + colb + q * 4 + 1] = f2h(va.y);
            Ah[row * 72 + colb + q * 4 + 2] = f2h(va.z);
            Ah[row * 72 + colb + q * 4 + 3] = f2h(va.w);
            float4 vb = *(const float4*)(Bb + (size_t)row * 64 + colb + q * 4);
            Bh[row * 72 + colb + q * 4 + 0] = f2h(vb.x);
            Bh[row * 72 + colb + q * 4 + 1] = f2h(vb.y);
            Bh[row * 72 + colb + q * 4 + 2] = f2h(vb.z);
            Bh[row * 72 + colb + q * 4 + 3] = f2h(vb.w);
        }
    }
    __syncthreads();

    for (int ci = 0; ci < 16; ++ci) {
        const int c = cg * 16 + ci;
        u16* tb = &Tt[ci & 1][0];

        // GEMM1: rows u (from Bh), cols j (V rows from global), K = w (64)
        f32x4 acc1[2][2];
        #pragma unroll
        for (int i = 0; i < 2; ++i)
            #pragma unroll
            for (int j = 0; j < 2; ++j) acc1[i][j] = (f32x4){0.f, 0.f, 0.f, 0.f};
        #pragma unroll
        for (int s = 0; s < 2; ++s) {
            f16x8 a1[2], b1[2];
            #pragma unroll
            for (int i = 0; i < 2; ++i)
                a1[i] = *(const f16x8*)&Bh[(wr * 32 + i * 16 + l16) * 72 + s * 32 + quad * 8];
            #pragma unroll
            for (int j = 0; j < 2; ++j)
                b1[j] = *(const f16x8*)(Vb + (size_t)c * 4096 +
                                        (size_t)(wc * 32 + j * 16 + l16) * 64 + s * 32 + quad * 8);
            #pragma unroll
            for (int i = 0; i < 2; ++i)
                #pragma unroll
                for (int j = 0; j < 2; ++j)
                    acc1[i][j] = mfma16(a1[i], b1[j], acc1[i][j]);
        }
        #pragma unroll
        for (int i = 0; i < 2; ++i)
            #pragma unroll
            for (int j = 0; j < 2; ++j)
                #pragma unroll
                for (int r = 0; r < 4; ++r)
                    tb[(wr * 32 + i * 16 + quad * 4 + r) * 72 + wc * 32 + j * 16 + l16] =
                        f2h(acc1[i][j][r]);
        __syncthreads();

        // GEMM2: rows i (from Ah), cols u (tmpT rows), K = j (64)
        f32x4 acc2[2][2];
        #pragma unroll
        for (int i = 0; i < 2; ++i)
            #pragma unroll
            for (int j = 0; j < 2; ++j) acc2[i][j] = (f32x4){0.f, 0.f, 0.f, 0.f};
        #pragma unroll
        for (int s = 0; s < 2; ++s) {
            f16x8 a2[2], b2[2];
            #pragma unroll
            for (int i = 0; i < 2; ++i)
                a2[i] = *(const f16x8*)&Ah[(wr * 32 + i * 16 + l16) * 72 + s * 32 + quad * 8];
            #pragma unroll
            for (int u = 0; u < 2; ++u)
                b2[u] = *(const f16x8*)&tb[(wc * 32 + u * 16 + l16) * 72 + s * 32 + quad * 8];
            #pragma unroll
            for (int i = 0; i < 2; ++i)
                #pragma unroll
                for (int u = 0; u < 2; ++u)
                    acc2[i][u] = mfma16(a2[i], b2[u], acc2[i][u]);
        }
        // stage out[i][u] f16 -> Ot, then coalesced 128B-row writes
        #pragma unroll
        for (int i = 0; i < 2; ++i)
            #pragma unroll
            for (int u = 0; u < 2; ++u)
                #pragma unroll
                for (int r = 0; r < 4; ++r)
                    Ot[(wr * 32 + i * 16 + quad * 4 + r) * 72 + wc * 32 + u * 16 + l16] =
                        f2h(acc2[i][u][r]);
        __syncthreads();
        {
            const int row0 = t >> 3, l8 = t & 7;
            #pragma unroll
            for (int pass = 0; pass < 2; ++pass) {
                const int row = pass * 32 + row0;
                *(float4*)(Yb + (size_t)c * 4096 + row * 64 + l8 * 8) =
                    *(const float4*)&Ot[row * 72 + l8 * 8];
            }
        }
        // next ci's tb-store barrier also protects Ot reuse
    }
}

// ---------------------------------------------------------------------------
// proj_mfma: Ytb[65536,512](f16) @ WpT(f16) + b -> Out fp32 [65536,512].
// BK=32, double-buffered stage-ahead, XCD swizzle. (fp32 stores are 64-B
// runs = full HBM granule -> left as-is.)
// ---------------------------------------------------------------------------
__global__ __launch_bounds__(256) void proj_mfma(
    const u16* __restrict__ A, const u16* __restrict__ WT,
    const float* __restrict__ bias, float* __restrict__ Out)
{
    __shared__ __align__(16) char smem[32768];   // 2x(As 8K + Bs 8K)

    const int id  = blockIdx.x;                  // 0..2047
    const int xcd = id & 7;
    const int jj  = id >> 3;                     // 0..255
    const int mt  = xcd * 64 + (jj >> 2);
    const int nt  = jj & 3;

    const int t = threadIdx.x;
    const int wave = t >> 6, lane = t & 63;
    const int wm = wave & 1, wn = wave >> 1;
    const int quad = lane >> 4, l16 = lane & 15;
    const int m0 = mt * 128;

    const int c0 = wave * 128 + lane;
    const int c1 = c0 + 64;
    const size_t aoff0 = (size_t)(m0 + (c0 & 127)) * 512 + (c0 >> 7) * 8;
    const size_t aoff1 = (size_t)(m0 + (c1 & 127)) * 512 + (c1 >> 7) * 8;
    const size_t woff0 = (size_t)(nt * 128 + (c0 & 127)) * 512 + (c0 >> 7) * 8;
    const size_t woff1 = (size_t)(nt * 128 + (c1 & 127)) * 512 + (c1 >> 7) * 8;
    const int lb0 = (wave * 128) * 16;
    const int lb1 = lb0 + 64 * 16;

    f32x4 acc[4][4];
    #pragma unroll
    for (int i = 0; i < 4; ++i)
        #pragma unroll
        for (int j = 0; j < 4; ++j) acc[i][j] = (f32x4){0.f, 0.f, 0.f, 0.f};

    glds16(A  + aoff0, smem + lb0);
    glds16(A  + aoff1, smem + lb1);
    glds16(WT + woff0, smem + 8192 + lb0);
    glds16(WT + woff1, smem + 8192 + lb1);
    __syncthreads();

    for (int k0 = 0; k0 < 512; k0 += 32) {
        const int co = (k0 & 32) << 9;
        const int cn = co ^ 16384;
        char* Ac = smem + co;
        char* Bc = smem + 8192 + co;
        if (k0 < 480) {
            glds16(A  + aoff0 + k0 + 32, smem + cn + lb0);
            glds16(A  + aoff1 + k0 + 32, smem + cn + lb1);
            glds16(WT + woff0 + k0 + 32, smem + 8192 + cn + lb0);
            glds16(WT + woff1 + k0 + 32, smem + 8192 + cn + lb1);
        }

        f16x8 af[4], bf[4];
        #pragma unroll
        for (int i = 0; i < 4; ++i)
            af[i] = *(const f16x8*)(Ac + (quad * 128 + wm * 64 + i * 16 + l16) * 16);
        #pragma unroll
        for (int j = 0; j < 4; ++j)
            bf[j] = *(const f16x8*)(Bc + (quad * 128 + wn * 64 + j * 16 + l16) * 16);
        #pragma unroll
        for (int i = 0; i < 4; ++i)
            #pragma unroll
            for (int j = 0; j < 4; ++j)
                acc[i][j] = mfma16(af[i], bf[j], acc[i][j]);

        __syncthreads();
    }

    float bv[4];
    #pragma unroll
    for (int j = 0; j < 4; ++j) bv[j] = bias[nt * 128 + wn * 64 + j * 16 + l16];

    #pragma unroll
    for (int i = 0; i < 4; ++i) {
        const int rowb = m0 + wm * 64 + i * 16 + quad * 4;
        #pragma unroll
        for (int j = 0; j < 4; ++j) {
            const int col = nt * 128 + wn * 64 + j * 16 + l16;
            #pragma unroll
            for (int r = 0; r < 4; ++r)
                Out[(size_t)(rowb + r) * 512 + col] = acc[i][j][r] + bv[j];
        }
    }
}

// ---------------------------------------------------------------------------
extern "C" void kernel_launch(void* const* d_in, const int* in_sizes, int n_in,
                              void* d_out, int out_size, void* d_ws, size_t ws_size,
                              hipStream_t stream)
{
    const float* x     = (const float*)d_in[0];
    const float* Wqkv  = (const float*)d_in[1];
    const float* bqkv  = (const float*)d_in[2];
    const float* Wproj = (const float*)d_in[3];
    const float* bproj = (const float*)d_in[4];
    float* out = (float*)d_out;

    u16* Xh  = (u16*)d_ws;                  // 33554432 elems (64 MB)
    u16* Qh  = Xh + 33554432;
    u16* Kh  = Qh + 33554432;
    u16* Vth = Kh + 33554432;
    u16* WqT = Vth + 33554432;              // 786432
    u16* WpT = WqT + 786432;                // 262144
    float* Aa = (float*)(WpT + 262144);     // 524288 f
    float* Bm = Aa + 524288;                // 524288 f
    u16* Yh  = Xh;                          // 64 MB f16, aliases Xh (dead after qkv)
    u16* Ytb = Kh;                          // aliases Kh (dead after attn)

    to_f16        <<<16384, 256, 0, stream>>>(x, Xh);
    transpose_f16 <<<dim3(24, 8, 1),  256, 0, stream>>>(Wqkv,  WqT, 512, 1536);
    transpose_f16 <<<dim3(8, 8, 1),   256, 0, stream>>>(Wproj, WpT, 512, 512);
    qkv_mfma      <<<1536,            512, 0, stream>>>(Xh, WqT, bqkv, Qh, Kh, Vth);
    attn_logits   <<<dim3(128, 2),    256, 0, stream>>>(Qh, Kh, Aa, Bm);
    coupling      <<<dim3(128, 4),    256, 0, stream>>>(Vth, Aa, Bm, Yh);
    transpose16   <<<dim3(64, 8, 16), 256, 0, stream>>>(Yh, Ytb);
    proj_mfma     <<<2048,            256, 0, stream>>>(Ytb, WpT, bproj, out);
}

// Round 8
// 641.884 us; speedup vs baseline: 1.2635x; 1.0104x over previous
//
#include <hip/hip_runtime.h>
#include <math.h>

#define SCALE_F 0.35355339059327373f   // 64^-0.25

typedef unsigned short u16;
typedef unsigned int   u32;
typedef _Float16 f16;
typedef _Float16 f16x8 __attribute__((ext_vector_type(8)));
typedef float    f32x4 __attribute__((ext_vector_type(4)));

__device__ __forceinline__ u16 f2h(float f) { f16 h = (f16)f; return *(u16*)&h; }
__device__ __forceinline__ float h2f(u16 b) { f16 h = *(f16*)&b; return (float)h; }

__device__ __forceinline__ void glds16(const u16* g, char* l) {
    __builtin_amdgcn_global_load_lds((const __attribute__((address_space(1))) void*)g,
                                     (__attribute__((address_space(3))) void*)l, 16, 0, 0);
}
__device__ __forceinline__ f32x4 mfma16(f16x8 a, f16x8 b, f32x4 c) {
    return __builtin_amdgcn_mfma_f32_16x16x32_f16(a, b, c, 0, 0, 0);
}

// ---------------------------------------------------------------------------
// to_f16: fp32 -> f16 elementwise (8 elems/thread).
// ---------------------------------------------------------------------------
__global__ __launch_bounds__(256) void to_f16(
    const float* __restrict__ X, u16* __restrict__ out)
{
    size_t i = ((size_t)blockIdx.x * 256 + threadIdx.x) * 8;
    float4 a = *(const float4*)(X + i);
    float4 b = *(const float4*)(X + i + 4);
    ushort4 r0, r1;
    r0.x = f2h(a.x); r0.y = f2h(a.y); r0.z = f2h(a.z); r0.w = f2h(a.w);
    r1.x = f2h(b.x); r1.y = f2h(b.y); r1.z = f2h(b.z); r1.w = f2h(b.w);
    *(ushort4*)(out + i)     = r0;
    *(ushort4*)(out + i + 4) = r1;
}

// ---------------------------------------------------------------------------
// transpose_f16: in [Z][R][C] fp32 -> out [Z][C][R] f16. 64x64 LDS tiles.
// ---------------------------------------------------------------------------
__global__ __launch_bounds__(256) void transpose_f16(
    const float* __restrict__ in, u16* __restrict__ out, int R, int C)
{
    __shared__ __align__(16) u16 T[64 * 80];
    const int c0 = blockIdx.x * 64, r0 = blockIdx.y * 64, z = blockIdx.z;
    const int t = threadIdx.x;
    const int rl = t >> 4, c4 = (t & 15) * 4;
    const float* base = in + (size_t)z * R * C;

    #pragma unroll
    for (int rr = 0; rr < 4; ++rr) {
        int r = rr * 16 + rl;
        float4 v = *(const float4*)(base + (size_t)(r0 + r) * C + c0 + c4);
        T[(c4 + 0) * 80 + r] = f2h(v.x);
        T[(c4 + 1) * 80 + r] = f2h(v.y);
        T[(c4 + 2) * 80 + r] = f2h(v.z);
        T[(c4 + 3) * 80 + r] = f2h(v.w);
    }
    __syncthreads();
    #pragma unroll
    for (int rep = 0; rep < 2; ++rep) {
        int idx = rep * 256 + t;
        int cl = idx >> 3, r8 = (idx & 7) * 8;
        *(float4*)(out + ((size_t)z * C + c0 + cl) * R + r0 + r8) =
            *(const float4*)&T[cl * 80 + r8];
    }
}

// ---------------------------------------------------------------------------
// transpose16: in [Z=16][512][4096] f16 -> out [Z][4096][512] f16.
// 64x64 tiles through padded LDS.
// ---------------------------------------------------------------------------
__global__ __launch_bounds__(256) void transpose16(
    const u16* __restrict__ in, u16* __restrict__ out)
{
    __shared__ __align__(16) u16 T[64 * 80];
    const int c0 = blockIdx.x * 64, r0 = blockIdx.y * 64, z = blockIdx.z;
    const int t = threadIdx.x;
    const int rl = t >> 3;          // 0..31
    const int c8 = (t & 7) * 8;     // col chunk base
    const u16* base = in + (size_t)z * 512 * 4096;

    #pragma unroll
    for (int rr = 0; rr < 2; ++rr) {
        int r = rr * 32 + rl;
        const u16* p = base + (size_t)(r0 + r) * 4096 + c0 + c8;
        ushort4 v0 = *(const ushort4*)(p);
        ushort4 v1 = *(const ushort4*)(p + 4);
        T[(c8 + 0) * 80 + r] = v0.x;
        T[(c8 + 1) * 80 + r] = v0.y;
        T[(c8 + 2) * 80 + r] = v0.z;
        T[(c8 + 3) * 80 + r] = v0.w;
        T[(c8 + 4) * 80 + r] = v1.x;
        T[(c8 + 5) * 80 + r] = v1.y;
        T[(c8 + 6) * 80 + r] = v1.z;
        T[(c8 + 7) * 80 + r] = v1.w;
    }
    __syncthreads();
    #pragma unroll
    for (int rep = 0; rep < 2; ++rep) {
        int idx = rep * 256 + t;
        int cl = idx >> 3, r8 = (idx & 7) * 8;
        *(float4*)(out + ((size_t)z * 4096 + c0 + cl) * 512 + r0 + r8) =
            *(const float4*)&T[cl * 80 + r8];
    }
}

// ---------------------------------------------------------------------------
// qkv_mfma: Xh[65536,512](f16) @ WT(f16) + b.  256x256 tile, BK=32, 8 waves
// (2x4, per-wave 128x64), 16x16x32 f16 MFMA.
// Round-8 K-loop: COUNTED-VMCNT RING (T4).  4-slot LDS ring (4 x 32KB),
// prefetch distance 3.  Per phase: s_waitcnt vmcnt(8) [tiles t+1,t+2 stay in
// flight across the barrier -- never drain to 0 until the tail] -> raw
// s_barrier -> sched_barrier(0) -> stage tile t+3 -> ds_read + 32 MFMA.
// WAR safe: slot (t+3)&3 last read in phase t-1, separated by barrier t.
// Visibility: per-wave vmcnt retirement + s_barrier (m201-verified).
// Epilogue unchanged from r7 (coalesced Q/K via wave-private XOR-swizzled
// LDS transpose -- slots 0/1 only; K-loop's last reads are slots 2/3).
// ---------------------------------------------------------------------------
__global__ __launch_bounds__(512) void qkv_mfma(
    const u16* __restrict__ Xh, const u16* __restrict__ WT,
    const float* __restrict__ bias,
    u16* __restrict__ Q, u16* __restrict__ Kk, u16* __restrict__ Vt)
{
    __shared__ __align__(16) char smem[131072];  // 4 ring slots x (A 16K + B 16K)

    const int id  = blockIdx.x;                  // 0..1535
    const int xcd = id & 7;
    const int jj  = id >> 3;                     // 0..191
    const int mt  = xcd * 32 + jj / 6;           // 0..255
    const int nt  = jj % 6;                      // 0..5

    const int t = threadIdx.x;
    const int wave = t >> 6, lane = t & 63;
    const int wm = wave & 1, wn = wave >> 1;     // 2x4 wave grid: 128 rows x 64 cols each
    const int quad = lane >> 4, l16 = lane & 15;
    const int m0 = mt * 256;

    const int srow = (wave & 3) * 64 + lane;
    size_t xoff[2], woff[2];
    int lb[2];
    #pragma unroll
    for (int p = 0; p < 2; ++p) {
        const int oct = p * 2 + (wave >> 2);
        xoff[p] = (size_t)(m0 + srow) * 512 + oct * 8;
        woff[p] = (size_t)(nt * 256 + srow) * 512 + oct * 8;
        lb[p]   = (p * 512 + wave * 64) * 16;
    }

    f32x4 acc[8][4];
    #pragma unroll
    for (int i = 0; i < 8; ++i)
        #pragma unroll
        for (int j = 0; j < 4; ++j) acc[i][j] = (f32x4){0.f, 0.f, 0.f, 0.f};

#define STAGE_QKV(T, S) do {                                                 \
        char* _d = smem + (S) * 32768;                                       \
        const int _k = (T) * 32;                                             \
        glds16(Xh + xoff[0] + _k, _d + lb[0]);                               \
        glds16(Xh + xoff[1] + _k, _d + lb[1]);                               \
        glds16(WT + woff[0] + _k, _d + 16384 + lb[0]);                       \
        glds16(WT + woff[1] + _k, _d + 16384 + lb[1]);                       \
    } while (0)

#define COMPUTE_QKV(S) do {                                                  \
        char* _Ac = smem + (S) * 32768;                                      \
        char* _Bc = _Ac + 16384;                                             \
        f16x8 _af[8], _bf[4];                                                \
        _Pragma("unroll")                                                    \
        for (int _i = 0; _i < 8; ++_i)                                       \
            _af[_i] = *(const f16x8*)(_Ac + (quad * 256 + wm * 128 + _i * 16 + l16) * 16); \
        _Pragma("unroll")                                                    \
        for (int _j = 0; _j < 4; ++_j)                                       \
            _bf[_j] = *(const f16x8*)(_Bc + (quad * 256 + wn * 64 + _j * 16 + l16) * 16);  \
        __builtin_amdgcn_s_setprio(1);                                       \
        _Pragma("unroll")                                                    \
        for (int _i = 0; _i < 8; ++_i)                                       \
            _Pragma("unroll")                                                \
            for (int _j = 0; _j < 4; ++_j)                                   \
                acc[_i][_j] = mfma16(_af[_i], _bf[_j], acc[_i][_j]);         \
        __builtin_amdgcn_s_setprio(0);                                       \
    } while (0)

    // prologue: stage tiles 0..2 into slots 0..2 (12 glds16/wave outstanding)
    STAGE_QKV(0, 0);
    STAGE_QKV(1, 1);
    STAGE_QKV(2, 2);

    for (int kt = 0; kt < 13; ++kt) {            // tiles 0..12, stage 3..15
        asm volatile("s_waitcnt vmcnt(8)" ::: "memory");
        __builtin_amdgcn_s_barrier();
        __builtin_amdgcn_sched_barrier(0);
        STAGE_QKV(kt + 3, (kt + 3) & 3);
        COMPUTE_QKV(kt & 3);
    }
    // tile 13 (slot 1): tiles 14,15 in flight
    asm volatile("s_waitcnt vmcnt(8)" ::: "memory");
    __builtin_amdgcn_s_barrier();
    __builtin_amdgcn_sched_barrier(0);
    COMPUTE_QKV(1);
    // tile 14 (slot 2): tile 15 in flight
    asm volatile("s_waitcnt vmcnt(4)" ::: "memory");
    __builtin_amdgcn_s_barrier();
    __builtin_amdgcn_sched_barrier(0);
    COMPUTE_QKV(2);
    // tile 15 (slot 3): drain
    asm volatile("s_waitcnt vmcnt(0)" ::: "memory");
    __builtin_amdgcn_s_barrier();
    __builtin_amdgcn_sched_barrier(0);
    COMPUTE_QKV(3);

#undef STAGE_QKV
#undef COMPUTE_QKV

    const int b   = m0 >> 12;
    const int nn0 = m0 & 4095;
    float bv[4];
    #pragma unroll
    for (int j = 0; j < 4; ++j) bv[j] = bias[nt * 256 + wn * 64 + j * 16 + l16];

    if (nt < 4) {
        // per-wave LDS transpose -> coalesced float4 stores (wave-private 8KB
        // regions = slots 0/1; K-loop's last reads were slots 2/3, two
        // barriers upstream -> no hazard, no extra barrier needed)
        u16* dst = (nt < 2) ? Q : Kk;
        const int hh = (nt & 1) * 4 + wn;        // this wave's head
        char* Tw = smem + wave * 8192;           // [64 rows][128 B], XOR-swizzled
        u16* dsth = dst + ((size_t)(b * 8 + hh) * 4096 + nn0 + wm * 128) * 64;
        const int r8 = lane >> 3, l8 = lane & 7;
        #pragma unroll
        for (int g = 0; g < 2; ++g) {
            #pragma unroll
            for (int i2 = 0; i2 < 4; ++i2) {
                const int i = g * 4 + i2;
                #pragma unroll
                for (int j = 0; j < 4; ++j) {
                    #pragma unroll
                    for (int r = 0; r < 4; ++r) {
                        const int rl = i2 * 16 + quad * 4 + r;       // 0..63
                        const int cb = (j * 16 + l16) * 2;           // byte col
                        *(u16*)(Tw + rl * 128 + (cb ^ ((rl & 7) << 4))) =
                            f2h(acc[i][j][r] + bv[j]);
                    }
                }
            }
            #pragma unroll
            for (int rep = 0; rep < 8; ++rep) {
                const int rl = rep * 8 + r8;                          // 0..63
                f16x8 v = *(const f16x8*)(Tw + rl * 128 + ((l8 * 16) ^ ((rl & 7) << 4)));
                *(float4*)(dsth + (size_t)(g * 64 + rl) * 64 + l8 * 8) = *(float4*)&v;
            }
        }
    } else {
        // V: per head-group g (=wn of owning waves), transpose 256n x 64d
        // through Trt[64][272] u16, then coalesced 16B writes to Vt.
        u16* Trt = (u16*)smem;                   // [64][272], 34816 B
        const int hb = (nt - 4) * 4;
        #pragma unroll
        for (int g = 0; g < 4; ++g) {
            __syncthreads();                     // WAR vs previous copy / K-loop
            if (wn == g) {
                #pragma unroll
                for (int i = 0; i < 8; ++i)
                    #pragma unroll
                    for (int j = 0; j < 4; ++j)
                        #pragma unroll
                        for (int r = 0; r < 4; ++r)
                            Trt[(j * 16 + l16) * 272 + wm * 128 + i * 16 + quad * 4 + r] =
                                f2h(acc[i][j][r] + bv[j]);
            }
            __syncthreads();
            const int h = hb + g;
            u16* dstv = Vt + ((size_t)(b * 8 + h) * 64) * 4096 + nn0;
            #pragma unroll
            for (int rep = 0; rep < 4; ++rep) {
                int idx = rep * 512 + t;
                int d = idx >> 5, r8v = (idx & 31) * 8;
                *(float4*)(dstv + (size_t)d * 4096 + r8v) =
                    *(const float4*)&Trt[d * 272 + r8v];
            }
        }
    }
}

// ---------------------------------------------------------------------------
// attn_logits (MFMA, no-LDS main loop): f16 Q,K in, fp32 softmaxed logits out.
// ---------------------------------------------------------------------------
__global__ __launch_bounds__(256) void attn_logits(
    const u16* __restrict__ Q, const u16* __restrict__ Kk,
    float* __restrict__ Aout, float* __restrict__ Bmout)
{
    __shared__ float sm[64 * 68];
    __shared__ float red[128];

    const int bh   = blockIdx.x;
    const int mode = blockIdx.y;
    const int t    = threadIdx.x;
    const int wave = t >> 6, lane = t & 63;
    const int wr = wave & 1, wc = wave >> 1;     // 2x2 wave grid, 32x32 per wave
    const int quad = lane >> 4, l16 = lane & 15;

    const u16* Qb = Q  + (size_t)bh * 262144;
    const u16* Kb = Kk + (size_t)bh * 262144;

    const int rA0 = wr * 32 + l16, rA1 = rA0 + 16;   // A rows (Q)
    const int rB0 = wc * 32 + l16, rB1 = rB0 + 16;   // B rows (K)

    f32x4 acc[2][2];
    #pragma unroll
    for (int i = 0; i < 2; ++i)
        #pragma unroll
        for (int j = 0; j < 2; ++j) acc[i][j] = (f32x4){0.f, 0.f, 0.f, 0.f};

    if (mode == 0) {
        const u16* pA0 = Qb + (size_t)rA0 * 4096;
        const u16* pA1 = Qb + (size_t)rA1 * 4096;
        const u16* pB0 = Kb + (size_t)rB0 * 4096;
        const u16* pB1 = Kb + (size_t)rB1 * 4096;
        #pragma unroll 4
        for (int k0 = 0; k0 < 4096; k0 += 32) {
            const int kk = k0 + quad * 8;
            f16x8 a0 = *(const f16x8*)(pA0 + kk);
            f16x8 a1 = *(const f16x8*)(pA1 + kk);
            f16x8 b0 = *(const f16x8*)(pB0 + kk);
            f16x8 b1 = *(const f16x8*)(pB1 + kk);
            acc[0][0] = mfma16(a0, b0, acc[0][0]);
            acc[0][1] = mfma16(a0, b1, acc[0][1]);
            acc[1][0] = mfma16(a1, b0, acc[1][0]);
            acc[1][1] = mfma16(a1, b1, acc[1][1]);
        }
    } else {
        #pragma unroll 4
        for (int k0 = 0; k0 < 4096; k0 += 32) {
            const int kk = k0 + quad * 8;
            const size_t base = (size_t)(kk >> 6) * 4096 + (kk & 63);
            f16x8 a0 = *(const f16x8*)(Qb + base + rA0 * 64);
            f16x8 a1 = *(const f16x8*)(Qb + base + rA1 * 64);
            f16x8 b0 = *(const f16x8*)(Kb + base + rB0 * 64);
            f16x8 b1 = *(const f16x8*)(Kb + base + rB1 * 64);
            acc[0][0] = mfma16(a0, b0, acc[0][0]);
            acc[0][1] = mfma16(a0, b1, acc[0][1]);
            acc[1][0] = mfma16(a1, b0, acc[1][0]);
            acc[1][1] = mfma16(a1, b1, acc[1][1]);
        }
    }

    #pragma unroll
    for (int i = 0; i < 2; ++i)
        #pragma unroll
        for (int j = 0; j < 2; ++j)
            #pragma unroll
            for (int r = 0; r < 4; ++r)
                sm[(wr * 32 + i * 16 + quad * 4 + r) * 68 + wc * 32 + j * 16 + l16] =
                    acc[i][j][r] * SCALE_F;
    __syncthreads();
    if (t < 64) {
        float m = -1e30f;
        for (int j = 0; j < 64; ++j) m = fmaxf(m, sm[t * 68 + j]);
        float ssum = 0.f;
        for (int j = 0; j < 64; ++j) ssum += __expf(sm[t * 68 + j] - m);
        red[t] = m;
        red[64 + t] = 1.0f / ssum;
    }
    __syncthreads();
    float* Out = ((mode == 0) ? Aout : Bmout) + (size_t)bh * 4096;
    #pragma unroll
    for (int rep = 0; rep < 16; ++rep) {
        int idx = rep * 256 + t;
        int i = idx >> 6, j = idx & 63;
        Out[idx] = __expf(sm[i * 68 + j] - red[i]) * red[64 + i];
    }
}

// ---------------------------------------------------------------------------
// coupling (MFMA): per (bh,c): out_c = A · (V_c · Bm^T).
// Output staged through Ot[64][72] -> coalesced float4 row writes.
// ---------------------------------------------------------------------------
__global__ __launch_bounds__(256) void coupling(
    const u16* __restrict__ Vt, const float* __restrict__ Aatt,
    const float* __restrict__ Bm, u16* __restrict__ Yh)
{
    __shared__ __align__(16) u16 Ah[64 * 72];
    __shared__ __align__(16) u16 Bh[64 * 72];
    __shared__ __align__(16) u16 Tt[2][64 * 72];
    __shared__ __align__(16) u16 Ot[64 * 72];

    const int bh = blockIdx.x, cg = blockIdx.y;
    const int t = threadIdx.x;
    const int wave = t >> 6, lane = t & 63;
    const int wr = wave & 1, wc = wave >> 1;
    const int quad = lane >> 4, l16 = lane & 15;

    const float* Ab = Aatt + (size_t)bh * 4096;
    const float* Bb = Bm   + (size_t)bh * 4096;
    const u16*  Vb  = Vt   + (size_t)bh * 262144;
    u16* Yb = Yh + (size_t)bh * 262144;

    {   // A[i][j], Bm[u][w] -> f16 LDS row-major stride 72
        const int row = t >> 2;
        const int colb = (t & 3) * 16;
        #pragma unroll
        for (int q = 0; q < 4; ++q) {
            float4 va = *(const float4*)(Ab + (size_t)row * 64 + colb + q * 4);
            Ah[row * 72 + colb + q * 4 + 0] = f2h(va.x);
            Ah[row * 72 + colb + q * 4 + 1] = f2h(va.y);
            Ah[row * 72 + colb + q * 4 + 2] = f2h(va.z);
            Ah[row * 72 + colb + q * 4 + 3] = f2h(va.w);
            float4 vb = *(const float4*)(Bb + (size_t)row * 64 + colb + q * 4);
            Bh[row * 72 + colb + q * 4 + 0] = f2h(vb.x);
            Bh[row * 72 + colb + q * 4 + 1] = f2h(vb.y);
            Bh[row * 72 + colb + q * 4 + 2] = f2h(vb.z);
            Bh[row * 72 + colb + q * 4 + 3] = f2h(vb.w);
        }
    }
    __syncthreads();

    for (int ci = 0; ci < 16; ++ci) {
        const int c = cg * 16 + ci;
        u16* tb = &Tt[ci & 1][0];

        // GEMM1: rows u (from Bh), cols j (V rows from global), K = w (64)
        f32x4 acc1[2][2];
        #pragma unroll
        for (int i = 0; i < 2; ++i)
            #pragma unroll
            for (int j = 0; j < 2; ++j) acc1[i][j] = (f32x4){0.f, 0.f, 0.f, 0.f};
        #pragma unroll
        for (int s = 0; s < 2; ++s) {
            f16x8 a1[2], b1[2];
            #pragma unroll
            for (int i = 0; i < 2; ++i)
                a1[i] = *(const f16x8*)&Bh[(wr * 32 + i * 16 + l16) * 72 + s * 32 + quad * 8];
            #pragma unroll
            for (int j = 0; j < 2; ++j)
                b1[j] = *(const f16x8*)(Vb + (size_t)c * 4096 +
                                        (size_t)(wc * 32 + j * 16 + l16) * 64 + s * 32 + quad * 8);
            #pragma unroll
            for (int i = 0; i < 2; ++i)
                #pragma unroll
                for (int j = 0; j < 2; ++j)
                    acc1[i][j] = mfma16(a1[i], b1[j], acc1[i][j]);
        }
        #pragma unroll
        for (int i = 0; i < 2; ++i)
            #pragma unroll
            for (int j = 0; j < 2; ++j)
                #pragma unroll
                for (int r = 0; r < 4; ++r)
                    tb[(wr * 32 + i * 16 + quad * 4 + r) * 72 + wc * 32 + j * 16 + l16] =
                        f2h(acc1[i][j][r]);
        __syncthreads();

        // GEMM2: rows i (from Ah), cols u (tmpT rows), K = j (64)
        f32x4 acc2[2][2];
        #pragma unroll
        for (int i = 0; i < 2; ++i)
            #pragma unroll
            for (int j = 0; j < 2; ++j) acc2[i][j] = (f32x4){0.f, 0.f, 0.f, 0.f};
        #pragma unroll
        for (int s = 0; s < 2; ++s) {
            f16x8 a2[2], b2[2];
            #pragma unroll
            for (int i = 0; i < 2; ++i)
                a2[i] = *(const f16x8*)&Ah[(wr * 32 + i * 16 + l16) * 72 + s * 32 + quad * 8];
            #pragma unroll
            for (int u = 0; u < 2; ++u)
                b2[u] = *(const f16x8*)&tb[(wc * 32 + u * 16 + l16) * 72 + s * 32 + quad * 8];
            #pragma unroll
            for (int i = 0; i < 2; ++i)
                #pragma unroll
                for (int u = 0; u < 2; ++u)
                    acc2[i][u] = mfma16(a2[i], b2[u], acc2[i][u]);
        }
        // stage out[i][u] f16 -> Ot, then coalesced 128B-row writes
        #pragma unroll
        for (int i = 0; i < 2; ++i)
            #pragma unroll
            for (int u = 0; u < 2; ++u)
                #pragma unroll
                for (int r = 0; r < 4; ++r)
                    Ot[(wr * 32 + i * 16 + quad * 4 + r) * 72 + wc * 32 + u * 16 + l16] =
                        f2h(acc2[i][u][r]);
        __syncthreads();
        {
            const int row0 = t >> 3, l8 = t & 7;
            #pragma unroll
            for (int pass = 0; pass < 2; ++pass) {
                const int row = pass * 32 + row0;
                *(float4*)(Yb + (size_t)c * 4096 + row * 64 + l8 * 8) =
                    *(const float4*)&Ot[row * 72 + l8 * 8];
            }
        }
        // next ci's tb-store barrier also protects Ot reuse
    }
}

// ---------------------------------------------------------------------------
// proj_mfma: Ytb[65536,512](f16) @ WpT(f16) + b -> Out fp32 [65536,512].
// 128x128 tile, BK=32.  Round-8: same counted-vmcnt 4-slot ring as qkv
// (4 x 16KB = 64KB LDS, 2 blocks/CU).  XCD swizzle.
// ---------------------------------------------------------------------------
__global__ __launch_bounds__(256) void proj_mfma(
    const u16* __restrict__ A, const u16* __restrict__ WT,
    const float* __restrict__ bias, float* __restrict__ Out)
{
    __shared__ __align__(16) char smem[65536];   // 4 ring slots x (A 8K + B 8K)

    const int id  = blockIdx.x;                  // 0..2047
    const int xcd = id & 7;
    const int jj  = id >> 3;                     // 0..255
    const int mt  = xcd * 64 + (jj >> 2);
    const int nt  = jj & 3;

    const int t = threadIdx.x;
    const int wave = t >> 6, lane = t & 63;
    const int wm = wave & 1, wn = wave >> 1;
    const int quad = lane >> 4, l16 = lane & 15;
    const int m0 = mt * 128;

    const int c0 = wave * 128 + lane;
    const int c1 = c0 + 64;
    const size_t aoff0 = (size_t)(m0 + (c0 & 127)) * 512 + (c0 >> 7) * 8;
    const size_t aoff1 = (size_t)(m0 + (c1 & 127)) * 512 + (c1 >> 7) * 8;
    const size_t woff0 = (size_t)(nt * 128 + (c0 & 127)) * 512 + (c0 >> 7) * 8;
    const size_t woff1 = (size_t)(nt * 128 + (c1 & 127)) * 512 + (c1 >> 7) * 8;
    const int lb0 = (wave * 128) * 16;
    const int lb1 = lb0 + 64 * 16;

    f32x4 acc[4][4];
    #pragma unroll
    for (int i = 0; i < 4; ++i)
        #pragma unroll
        for (int j = 0; j < 4; ++j) acc[i][j] = (f32x4){0.f, 0.f, 0.f, 0.f};

#define STAGE_P(T, S) do {                                                   \
        char* _d = smem + (S) * 16384;                                       \
        const int _k = (T) * 32;                                             \
        glds16(A  + aoff0 + _k, _d + lb0);                                   \
        glds16(A  + aoff1 + _k, _d + lb1);                                   \
        glds16(WT + woff0 + _k, _d + 8192 + lb0);                            \
        glds16(WT + woff1 + _k, _d + 8192 + lb1);                            \
    } while (0)

#define COMPUTE_P(S) do {                                                    \
        char* _Ac = smem + (S) * 16384;                                      \
        char* _Bc = _Ac + 8192;                                              \
        f16x8 _af[4], _bf[4];                                                \
        _Pragma("unroll")                                                    \
        for (int _i = 0; _i < 4; ++_i)                                       \
            _af[_i] = *(const f16x8*)(_Ac + (quad * 128 + wm * 64 + _i * 16 + l16) * 16); \
        _Pragma("unroll")                                                    \
        for (int _j = 0; _j < 4; ++_j)                                       \
            _bf[_j] = *(const f16x8*)(_Bc + (quad * 128 + wn * 64 + _j * 16 + l16) * 16); \
        __builtin_amdgcn_s_setprio(1);                                       \
        _Pragma("unroll")                                                    \
        for (int _i = 0; _i < 4; ++_i)                                       \
            _Pragma("unroll")                                                \
            for (int _j = 0; _j < 4; ++_j)                                   \
                acc[_i][_j] = mfma16(_af[_i], _bf[_j], acc[_i][_j]);         \
        __builtin_amdgcn_s_setprio(0);                                       \
    } while (0)

    STAGE_P(0, 0);
    STAGE_P(1, 1);
    STAGE_P(2, 2);

    for (int kt = 0; kt < 13; ++kt) {
        asm volatile("s_waitcnt vmcnt(8)" ::: "memory");
        __builtin_amdgcn_s_barrier();
        __builtin_amdgcn_sched_barrier(0);
        STAGE_P(kt + 3, (kt + 3) & 3);
        COMPUTE_P(kt & 3);
    }
    asm volatile("s_waitcnt vmcnt(8)" ::: "memory");
    __builtin_amdgcn_s_barrier();
    __builtin_amdgcn_sched_barrier(0);
    COMPUTE_P(1);
    asm volatile("s_waitcnt vmcnt(4)" ::: "memory");
    __builtin_amdgcn_s_barrier();
    __builtin_amdgcn_sched_barrier(0);
    COMPUTE_P(2);
    asm volatile("s_waitcnt vmcnt(0)" ::: "memory");
    __builtin_amdgcn_s_barrier();
    __builtin_amdgcn_sched_barrier(0);
    COMPUTE_P(3);

#undef STAGE_P
#undef COMPUTE_P

    float bv[4];
    #pragma unroll
    for (int j = 0; j < 4; ++j) bv[j] = bias[nt * 128 + wn * 64 + j * 16 + l16];

    #pragma unroll
    for (int i = 0; i < 4; ++i) {
        const int rowb = m0 + wm * 64 + i * 16 + quad * 4;
        #pragma unroll
        for (int j = 0; j < 4; ++j) {
            const int col = nt * 128 + wn * 64 + j * 16 + l16;
            #pragma unroll
            for (int r = 0; r < 4; ++r)
                Out[(size_t)(rowb + r) * 512 + col] = acc[i][j][r] + bv[j];
        }
    }
}

// ---------------------------------------------------------------------------
extern "C" void kernel_launch(void* const* d_in, const int* in_sizes, int n_in,
                              void* d_out, int out_size, void* d_ws, size_t ws_size,
                              hipStream_t stream)
{
    const float* x     = (const float*)d_in[0];
    const float* Wqkv  = (const float*)d_in[1];
    const float* bqkv  = (const float*)d_in[2];
    const float* Wproj = (const float*)d_in[3];
    const float* bproj = (const float*)d_in[4];
    float* out = (float*)d_out;

    u16* Xh  = (u16*)d_ws;                  // 33554432 elems (64 MB)
    u16* Qh  = Xh + 33554432;
    u16* Kh  = Qh + 33554432;
    u16* Vth = Kh + 33554432;
    u16* WqT = Vth + 33554432;              // 786432
    u16* WpT = WqT + 786432;                // 262144
    float* Aa = (float*)(WpT + 262144);     // 524288 f
    float* Bm = Aa + 524288;                // 524288 f
    u16* Yh  = Xh;                          // 64 MB f16, aliases Xh (dead after qkv)
    u16* Ytb = Kh;                          // aliases Kh (dead after attn)

    to_f16        <<<16384, 256, 0, stream>>>(x, Xh);
    transpose_f16 <<<dim3(24, 8, 1),  256, 0, stream>>>(Wqkv,  WqT, 512, 1536);
    transpose_f16 <<<dim3(8, 8, 1),   256, 0, stream>>>(Wproj, WpT, 512, 512);
    qkv_mfma      <<<1536,            512, 0, stream>>>(Xh, WqT, bqkv, Qh, Kh, Vth);
    attn_logits   <<<dim3(128, 2),    256, 0, stream>>>(Qh, Kh, Aa, Bm);
    coupling      <<<dim3(128, 4),    256, 0, stream>>>(Vth, Aa, Bm, Yh);
    transpose16   <<<dim3(64, 8, 16), 256, 0, stream>>>(Yh, Ytb);
    proj_mfma     <<<2048,            256, 0, stream>>>(Ytb, WpT, bproj, out);
}